// Round 9
// baseline (8555.329 us; speedup 1.0000x reference)
//
#include <hip/hip_runtime.h>

#define HID 64
#define IN_DIM 128
#define TAU_DIM 8
#define SCAN_B 1024

#define KDIM 128        // X row = [agg(64) | h(64)]
#define NT 64           // nodes per GEMM block
#define JOUT 256        // padded gate outputs: [rz(128) | i_n(64) | h_n(64)]
#define XS_STRIDE 132   // 128 + 4 pad (f32 words)
#define WS_STRIDE 20    // 16 + 4 pad (f32 words)

// ---------------- CSR build (bounds-guarded) ----------------

__global__ void zero_int_kernel(int* __restrict__ p, int n) {
    int i = blockIdx.x * blockDim.x + threadIdx.x;
    if (i < n) p[i] = 0;
}

__global__ void count_deg_kernel(const int* __restrict__ row, int* __restrict__ deg,
                                 int e, int n) {
    int i = blockIdx.x * blockDim.x + threadIdx.x;
    if (i < e) {
        int r = row[i];
        if ((unsigned)r < (unsigned)n) atomicAdd(&deg[r], 1);
    }
}

__global__ void block_sum_kernel(const int* __restrict__ deg, int* __restrict__ blk, int n) {
    __shared__ int s[SCAN_B];
    int i = blockIdx.x * SCAN_B + threadIdx.x;
    s[threadIdx.x] = (i < n) ? deg[i] : 0;
    __syncthreads();
    for (int off = SCAN_B / 2; off > 0; off >>= 1) {
        if (threadIdx.x < off) s[threadIdx.x] += s[threadIdx.x + off];
        __syncthreads();
    }
    if (threadIdx.x == 0) blk[blockIdx.x] = s[0];
}

__global__ void scan_blk_kernel(int* __restrict__ blk, int nb) {
    __shared__ int s[SCAN_B];
    int v = (threadIdx.x < nb) ? blk[threadIdx.x] : 0;
    s[threadIdx.x] = v;
    __syncthreads();
    for (int off = 1; off < SCAN_B; off <<= 1) {
        int t = (threadIdx.x >= off) ? s[threadIdx.x - off] : 0;
        __syncthreads();
        s[threadIdx.x] += t;
        __syncthreads();
    }
    if (threadIdx.x < nb) blk[threadIdx.x] = s[threadIdx.x] - v;  // exclusive
}

__global__ void scan_final_kernel(const int* __restrict__ deg, const int* __restrict__ blk,
                                  int* __restrict__ row_start, int* __restrict__ cursor, int n) {
    __shared__ int s[SCAN_B];
    int i = blockIdx.x * SCAN_B + threadIdx.x;
    int v = (i < n) ? deg[i] : 0;
    s[threadIdx.x] = v;
    __syncthreads();
    for (int off = 1; off < SCAN_B; off <<= 1) {
        int t = (threadIdx.x >= off) ? s[threadIdx.x - off] : 0;
        __syncthreads();
        s[threadIdx.x] += t;
        __syncthreads();
    }
    if (i < n) {
        int excl = s[threadIdx.x] - v + blk[blockIdx.x];
        row_start[i] = excl;
        cursor[i]    = excl;
    }
}

__global__ void fill_csr_kernel(const int* __restrict__ row, const int* __restrict__ col,
                                int* __restrict__ cursor, int* __restrict__ cols,
                                int e, int n) {
    int i = blockIdx.x * blockDim.x + threadIdx.x;
    if (i < e) {
        int r = row[i];
        if ((unsigned)r < (unsigned)n) {
            int c = col[i];
            if ((unsigned)c >= (unsigned)n) c = 0;
            int p = atomicAdd(&cursor[r], 1);
            cols[p] = c;
        }
    }
}

// ---------------- weight repacks ----------------

__global__ void prep_all_kernel(
    const float* __restrict__ W_ih, const float* __restrict__ W_hh,
    const float* __restrict__ b_ih, const float* __restrict__ b_hh,
    const float* __restrict__ W_in, const float* __restrict__ b_in,
    const float* __restrict__ W_t1, const float* __restrict__ b_t1,
    const float* __restrict__ W_out,
    float* __restrict__ W2p, float* __restrict__ B2,
    float* __restrict__ W1p, float* __restrict__ B1,
    float* __restrict__ Wop) {
    int j = threadIdx.x;  // 256 threads, 1 block
    {
        float b;
        if (j < 128)      b = b_ih[j] + b_hh[j];
        else if (j < 192) b = b_ih[j];
        else              b = b_hh[j - 64];
        B2[j] = b;
        for (int k = 0; k < KDIM; k++) {
            float v;
            if (j < 128)      v = (k < 64) ? W_ih[j * 64 + k] : W_hh[j * 64 + (k - 64)];
            else if (j < 192) v = (k < 64) ? W_ih[j * 64 + k] : 0.f;
            else              v = (k >= 64) ? W_hh[(j - 64) * 64 + (k - 64)] : 0.f;
            W2p[(size_t)(k >> 4) * (JOUT * 16) + j * 16 + (k & 15)] = v;
        }
    }
    if (j < 128) {
        B1[j] = (j < 64) ? b_in[j] : b_t1[j - 64];
        const float* src = (j < 64) ? (W_in + (size_t)j * IN_DIM)
                                    : (W_t1 + (size_t)(j - 64) * IN_DIM);
        for (int k = 0; k < IN_DIM; k++)
            W1p[(size_t)(k >> 4) * (128 * 16) + j * 16 + (k & 15)] = src[k];
    }
    if (j < 64) {
        for (int k = 0; k < HID; k++)
            Wop[(size_t)(k >> 4) * (64 * 16) + j * 16 + (k & 15)] = W_out[(size_t)j * HID + k];
    }
}

// ---------------- init as tiled GEMM: h0 + tau ----------------
// t1 scratch ALIASES the x-tile LDS (dead after the GEMM loop): 44 KB total
// -> 3 blocks/CU.

__global__ __launch_bounds__(256, 3) void init_gemm_kernel(
    const float* __restrict__ x, const float* __restrict__ W1p,
    const float* __restrict__ B1,
    const float* __restrict__ W_t2, const float* __restrict__ b_t2,
    float* __restrict__ X1, float* __restrict__ tau, int n) {
    __shared__ float xs[NT * XS_STRIDE];     // 33 KB; reused as t1s [NT][65]
    __shared__ float wsh[128 * WS_STRIDE];   // 10 KB

    const int t  = threadIdx.x;
    const int tx = t & 15;
    const int ty = t >> 4;
    const int node0 = blockIdx.x * NT;

#pragma unroll
    for (int i = 0; i < 8; i++) {
        int f4 = i * 256 + t;
        int r  = f4 >> 5;
        int c4 = f4 & 31;
        float4 v = make_float4(0.f, 0.f, 0.f, 0.f);
        int node = node0 + r;
        if (node < n) v = *(const float4*)(x + (size_t)node * IN_DIM + c4 * 4);
        *(float4*)(xs + r * XS_STRIDE + c4 * 4) = v;
    }

    float acc[4][2][4];  // [nd][gb][i]; j = gb*64 + i*16 + tx
#pragma unroll
    for (int gb = 0; gb < 2; gb++)
#pragma unroll
        for (int i = 0; i < 4; i++) {
            float b = B1[gb * 64 + i * 16 + tx];
#pragma unroll
            for (int nd = 0; nd < 4; nd++) acc[nd][gb][i] = b;
        }

    const float* wbase = wsh + tx * WS_STRIDE;
#pragma unroll 1
    for (int kc = 0; kc < 8; kc++) {
        __syncthreads();
        {
            const float4* src = (const float4*)(W1p + (size_t)kc * (128 * 16));
#pragma unroll
            for (int i = 0; i < 2; i++) {
                int f4  = i * 256 + t;
                int row = f4 >> 2;
                int k4  = f4 & 3;
                *(float4*)(wsh + row * WS_STRIDE + k4 * 4) = src[f4];
            }
        }
        __syncthreads();
        const float* xbase = xs + (ty * 4) * XS_STRIDE + kc * 16;
#pragma unroll
        for (int k4 = 0; k4 < 4; k4++) {
            float4 xv[4];
#pragma unroll
            for (int nd = 0; nd < 4; nd++)
                xv[nd] = *(const float4*)(xbase + nd * XS_STRIDE + k4 * 4);
#pragma unroll
            for (int gb = 0; gb < 2; gb++)
#pragma unroll
                for (int i = 0; i < 4; i++) {
                    float4 w = *(const float4*)(wbase + (gb * 64 + i * 16) * WS_STRIDE + k4 * 4);
#pragma unroll
                    for (int nd = 0; nd < 4; nd++) {
                        acc[nd][gb][i] += w.x * xv[nd].x + w.y * xv[nd].y
                                        + w.z * xv[nd].z + w.w * xv[nd].w;
                    }
                }
        }
    }

    // xs is dead; reuse as t1s [NT][65]
    __syncthreads();
    float* t1s = xs;
#pragma unroll
    for (int nd = 0; nd < 4; nd++) {
        int r = ty * 4 + nd;
        int node = node0 + r;
#pragma unroll
        for (int i = 0; i < 4; i++) {
            float h0 = fmaxf(acc[nd][0][i], 0.f);
            float t1 = fmaxf(acc[nd][1][i], 0.f);
            if (node < n) X1[(size_t)node * KDIM + 64 + i * 16 + tx] = h0;
            t1s[r * 65 + i * 16 + tx] = t1;
        }
    }
    __syncthreads();

    if (t < NT) {
        int node = node0 + t;
        if (node < n) {
            float tsum = 0.f;
#pragma unroll 1
            for (int m = 0; m < TAU_DIM; m++) {
                float a = b_t2[m];
                const float* wr = W_t2 + (size_t)m * HID;
#pragma unroll
                for (int k = 0; k < HID; k++) a += wr[k] * t1s[t * 65 + k];
                tsum += 1.f / (1.f + expf(-a));
            }
            tau[node] = tsum * (1.f / TAU_DIM);
        }
    }
}

// ---------------- aggregate: X1[v][aoff..] = tau[v] * sum |h[v]-h[col]| ----------------

__global__ __launch_bounds__(256) void aggregate_kernel(
    float* __restrict__ X1, const float* __restrict__ tau,
    const int* __restrict__ row_start, const int* __restrict__ deg,
    const int* __restrict__ cols, int n, int hoff, int aoff) {
    int t = blockIdx.x * blockDim.x + threadIdx.x;
    int v = t >> 4;
    if (v >= n) return;
    int c4 = (t & 15) * 4;

    float4 hv = *(const float4*)(X1 + (size_t)v * KDIM + hoff + c4);
    float4 s0 = make_float4(0.f, 0.f, 0.f, 0.f);
    float4 s1 = make_float4(0.f, 0.f, 0.f, 0.f);
    int st = row_start[v];
    int d  = deg[v];
    int i = 0;
    for (; i + 1 < d; i += 2) {
        int c0 = cols[st + i];
        int c1 = cols[st + i + 1];
        float4 hc0 = *(const float4*)(X1 + (size_t)c0 * KDIM + hoff + c4);
        float4 hc1 = *(const float4*)(X1 + (size_t)c1 * KDIM + hoff + c4);
        s0.x += fabsf(hv.x - hc0.x);
        s0.y += fabsf(hv.y - hc0.y);
        s0.z += fabsf(hv.z - hc0.z);
        s0.w += fabsf(hv.w - hc0.w);
        s1.x += fabsf(hv.x - hc1.x);
        s1.y += fabsf(hv.y - hc1.y);
        s1.z += fabsf(hv.z - hc1.z);
        s1.w += fabsf(hv.w - hc1.w);
    }
    if (i < d) {
        int c = cols[st + i];
        float4 hc = *(const float4*)(X1 + (size_t)c * KDIM + hoff + c4);
        s0.x += fabsf(hv.x - hc.x);
        s0.y += fabsf(hv.y - hc.y);
        s0.z += fabsf(hv.z - hc.z);
        s0.w += fabsf(hv.w - hc.w);
    }
    float tv = tau[v];
    *(float4*)(X1 + (size_t)v * KDIM + aoff + c4) =
        make_float4((s0.x + s1.x) * tv, (s0.y + s1.y) * tv,
                    (s0.z + s1.z) * tv, (s0.w + s1.w) * tv);
}

// ---------------- GRU as tiled GEMM + fused gating ----------------
// Round-9 change: k4 loop fully unrolled with hoisted LDS bases -> all
// ds_read_b128 get compile-time offset: immediates (kills per-iter address
// VALU). __launch_bounds__(256,3) caps VGPR at the 3-waves/SIMD budget so
// the unroll cannot re-trigger the round-5 spill cliff.

__global__ __launch_bounds__(256, 3) void gru_gemm_kernel(
    float* __restrict__ X1, const float* __restrict__ W2p,
    const float* __restrict__ B2, int n, int hoff, int aoff) {
    __shared__ float xs[NT * XS_STRIDE];    // 33 KB
    __shared__ float wsh[JOUT * WS_STRIDE]; // 20 KB

    const int t  = threadIdx.x;
    const int tx = t & 15;
    const int ty = t >> 4;
    const int node0 = blockIdx.x * NT;

    {
        const int aoff4 = aoff >> 2, hoff4 = hoff >> 2;
#pragma unroll
        for (int i = 0; i < 8; i++) {
            int f4 = i * 256 + t;
            int r  = f4 >> 5;
            int c4 = f4 & 31;
            int src4 = (c4 < 16) ? (aoff4 + c4) : (hoff4 + (c4 - 16));
            float4 v = make_float4(0.f, 0.f, 0.f, 0.f);
            int node = node0 + r;
            if (node < n) v = *(const float4*)(X1 + (size_t)node * KDIM + src4 * 4);
            *(float4*)(xs + r * XS_STRIDE + c4 * 4) = v;
        }
    }

    float acc[4][4][4];  // [nd][gate-quad][i]; j = gb*64 + i*16 + tx
#pragma unroll
    for (int gb = 0; gb < 4; gb++)
#pragma unroll
        for (int i = 0; i < 4; i++) {
            float b = B2[gb * 64 + i * 16 + tx];
#pragma unroll
            for (int nd = 0; nd < 4; nd++) acc[nd][gb][i] = b;
        }

    const float* wbase = wsh + tx * WS_STRIDE;
#pragma unroll 1
    for (int kc = 0; kc < 8; kc++) {
        __syncthreads();
        {
            const float4* src = (const float4*)(W2p + (size_t)kc * (JOUT * 16));
#pragma unroll
            for (int i = 0; i < 4; i++) {
                int f4  = i * 256 + t;
                int row = f4 >> 2;
                int k4  = f4 & 3;
                *(float4*)(wsh + row * WS_STRIDE + k4 * 4) = src[f4];
            }
        }
        __syncthreads();
        const float* xbase = xs + (ty * 4) * XS_STRIDE + kc * 16;
#pragma unroll
        for (int k4 = 0; k4 < 4; k4++) {
            float4 xv[4];
#pragma unroll
            for (int nd = 0; nd < 4; nd++)
                xv[nd] = *(const float4*)(xbase + nd * XS_STRIDE + k4 * 4);
#pragma unroll
            for (int gb = 0; gb < 4; gb++)
#pragma unroll
                for (int i = 0; i < 4; i++) {
                    float4 w = *(const float4*)(wbase + (gb * 64 + i * 16) * WS_STRIDE + k4 * 4);
#pragma unroll
                    for (int nd = 0; nd < 4; nd++) {
                        acc[nd][gb][i] += w.x * xv[nd].x + w.y * xv[nd].y
                                        + w.z * xv[nd].z + w.w * xv[nd].w;
                    }
                }
        }
    }

#pragma unroll
    for (int nd = 0; nd < 4; nd++) {
        int node = node0 + ty * 4 + nd;
        if (node < n) {
#pragma unroll
            for (int i = 0; i < 4; i++) {
                float r  = 1.f / (1.f + expf(-acc[nd][0][i]));
                float z  = 1.f / (1.f + expf(-acc[nd][1][i]));
                float nn = tanhf(acc[nd][2][i] + r * acc[nd][3][i]);
                float hold = xs[(ty * 4 + nd) * XS_STRIDE + 64 + i * 16 + tx];
                X1[(size_t)node * KDIM + aoff + i * 16 + tx] = (1.f - z) * nn + z * hold;
            }
        }
    }
}

// ---------------- output projection as tiled GEMM ----------------

__global__ __launch_bounds__(256) void out_gemm_kernel(
    const float* __restrict__ X1, const float* __restrict__ Wop,
    const float* __restrict__ b_out, float* __restrict__ out, int n, int hoff) {
    __shared__ float xs[NT * 68];          // 17.4 KB (64 + 4 pad)
    __shared__ float wsh[64 * WS_STRIDE];  // 5 KB

    const int t  = threadIdx.x;
    const int tx = t & 15;
    const int ty = t >> 4;
    const int node0 = blockIdx.x * NT;

#pragma unroll
    for (int i = 0; i < 4; i++) {
        int f4 = i * 256 + t;
        int r  = f4 >> 4;
        int c4 = f4 & 15;
        float4 v = make_float4(0.f, 0.f, 0.f, 0.f);
        int node = node0 + r;
        if (node < n) v = *(const float4*)(X1 + (size_t)node * KDIM + hoff + c4 * 4);
        *(float4*)(xs + r * 68 + c4 * 4) = v;
    }

    float acc[4][4];  // [nd][i]; j = i*16 + tx
#pragma unroll
    for (int i = 0; i < 4; i++) {
        float b = b_out[i * 16 + tx];
#pragma unroll
        for (int nd = 0; nd < 4; nd++) acc[nd][i] = b;
    }

    const float* wbase = wsh + tx * WS_STRIDE;
#pragma unroll 1
    for (int kc = 0; kc < 4; kc++) {
        __syncthreads();
        {
            const float4* src = (const float4*)(Wop + (size_t)kc * (64 * 16));
            int f4  = t;
            int row = f4 >> 2;
            int k4  = f4 & 3;
            *(float4*)(wsh + row * WS_STRIDE + k4 * 4) = src[f4];
        }
        __syncthreads();
        const float* xbase = xs + (ty * 4) * 68 + kc * 16;
#pragma unroll
        for (int k4 = 0; k4 < 4; k4++) {
            float4 xv[4];
#pragma unroll
            for (int nd = 0; nd < 4; nd++)
                xv[nd] = *(const float4*)(xbase + nd * 68 + k4 * 4);
#pragma unroll
            for (int i = 0; i < 4; i++) {
                float4 w = *(const float4*)(wbase + (i * 16) * WS_STRIDE + k4 * 4);
#pragma unroll
                for (int nd = 0; nd < 4; nd++) {
                    acc[nd][i] += w.x * xv[nd].x + w.y * xv[nd].y
                                + w.z * xv[nd].z + w.w * xv[nd].w;
                }
            }
        }
    }

#pragma unroll
    for (int nd = 0; nd < 4; nd++) {
        int node = node0 + ty * 4 + nd;
        if (node < n) {
#pragma unroll
            for (int i = 0; i < 4; i++)
                out[(size_t)node * HID + i * 16 + tx] = acc[nd][i];
        }
    }
}

// ---------------- launch ----------------

extern "C" void kernel_launch(void* const* d_in, const int* in_sizes, int n_in,
                              void* d_out, int out_size, void* d_ws, size_t ws_size,
                              hipStream_t stream) {
    const float* x     = (const float*)d_in[0];
    const int*   ei    = (const int*)d_in[1];
    const float* W_in  = (const float*)d_in[2];
    const float* b_in  = (const float*)d_in[3];
    const float* W_t1  = (const float*)d_in[4];
    const float* b_t1  = (const float*)d_in[5];
    const float* W_t2  = (const float*)d_in[6];
    const float* b_t2  = (const float*)d_in[7];
    const float* W_ih  = (const float*)d_in[8];
    const float* b_ih  = (const float*)d_in[9];
    const float* W_hh  = (const float*)d_in[10];
    const float* b_hh  = (const float*)d_in[11];
    const float* W_out = (const float*)d_in[12];
    const float* b_out = (const float*)d_in[13];
    float* out = (float*)d_out;

    const int n = in_sizes[0] / IN_DIM;  // 100000
    const int e = in_sizes[1] / 2;       // 1000000
    const int* row = ei;
    const int* col = ei + e;

    char* ws = (char*)d_ws;
    float* X1  = (float*)ws;  ws += (size_t)n * KDIM * sizeof(float);   // 51.2 MB
    float* W2p = (float*)ws;  ws += (size_t)JOUT * KDIM * sizeof(float);
    float* B2  = (float*)ws;  ws += JOUT * sizeof(float);
    float* W1p = (float*)ws;  ws += (size_t)128 * IN_DIM * sizeof(float);
    float* B1  = (float*)ws;  ws += 128 * sizeof(float);
    float* Wop = (float*)ws;  ws += (size_t)64 * HID * sizeof(float);
    float* tau = (float*)ws;  ws += (size_t)n * sizeof(float);
    int* deg       = (int*)ws;  ws += (size_t)n * sizeof(int);
    int* row_start = (int*)ws;  ws += (size_t)n * sizeof(int);
    int* cursor    = (int*)ws;  ws += (size_t)n * sizeof(int);
    int* blk       = (int*)ws;  ws += SCAN_B * sizeof(int);
    int* cols      = (int*)ws;  ws += (size_t)e * sizeof(int);

    const int nb = (n + SCAN_B - 1) / SCAN_B;
    const int ngemm = (n + NT - 1) / NT;

    zero_int_kernel<<<(n + 255) / 256, 256, 0, stream>>>(deg, n);
    count_deg_kernel<<<(e + 255) / 256, 256, 0, stream>>>(row, deg, e, n);
    block_sum_kernel<<<nb, SCAN_B, 0, stream>>>(deg, blk, n);
    scan_blk_kernel<<<1, SCAN_B, 0, stream>>>(blk, nb);
    scan_final_kernel<<<nb, SCAN_B, 0, stream>>>(deg, blk, row_start, cursor, n);
    fill_csr_kernel<<<(e + 255) / 256, 256, 0, stream>>>(row, col, cursor, cols, e, n);

    prep_all_kernel<<<1, 256, 0, stream>>>(W_ih, W_hh, b_ih, b_hh,
                                           W_in, b_in, W_t1, b_t1, W_out,
                                           W2p, B2, W1p, B1, Wop);
    init_gemm_kernel<<<ngemm, 256, 0, stream>>>(x, W1p, B1, W_t2, b_t2, X1, tau, n);

    int hoff = 64, aoff = 0;  // h starts in cols [64,128)
    for (int it = 0; it < 5; ++it) {
        aggregate_kernel<<<((n * 16) + 255) / 256, 256, 0, stream>>>(
            X1, tau, row_start, deg, cols, n, hoff, aoff);
        gru_gemm_kernel<<<ngemm, 256, 0, stream>>>(X1, W2p, B2, n, hoff, aoff);
        int tmp = hoff; hoff = aoff; aoff = tmp;  // h' now lives where agg was
    }
    out_gemm_kernel<<<ngemm, 256, 0, stream>>>(X1, Wop, b_out, out, n, hoff);
}

// Round 10
// 1657.499 us; speedup vs baseline: 5.1616x; 5.1616x over previous
//
#include <hip/hip_runtime.h>

#define HID 64
#define IN_DIM 128
#define TAU_DIM 8
#define SCAN_B 1024

#define KDIM 128        // X row = [agg(64) | h(64)]
#define NT 64           // nodes per GEMM block
#define JOUT 256        // padded gate outputs: [rz(128) | i_n(64) | h_n(64)]
#define XS_STRIDE 132   // 128 + 4 pad (f32 words)
#define WS_STRIDE 20    // 16 + 4 pad (f32 words)

// ---------------- CSR build (bounds-guarded) ----------------

__global__ void zero_int_kernel(int* __restrict__ p, int n) {
    int i = blockIdx.x * blockDim.x + threadIdx.x;
    if (i < n) p[i] = 0;
}

__global__ void count_deg_kernel(const int* __restrict__ row, int* __restrict__ deg,
                                 int e, int n) {
    int i = blockIdx.x * blockDim.x + threadIdx.x;
    if (i < e) {
        int r = row[i];
        if ((unsigned)r < (unsigned)n) atomicAdd(&deg[r], 1);
    }
}

__global__ void block_sum_kernel(const int* __restrict__ deg, int* __restrict__ blk, int n) {
    __shared__ int s[SCAN_B];
    int i = blockIdx.x * SCAN_B + threadIdx.x;
    s[threadIdx.x] = (i < n) ? deg[i] : 0;
    __syncthreads();
    for (int off = SCAN_B / 2; off > 0; off >>= 1) {
        if (threadIdx.x < off) s[threadIdx.x] += s[threadIdx.x + off];
        __syncthreads();
    }
    if (threadIdx.x == 0) blk[blockIdx.x] = s[0];
}

__global__ void scan_blk_kernel(int* __restrict__ blk, int nb) {
    __shared__ int s[SCAN_B];
    int v = (threadIdx.x < nb) ? blk[threadIdx.x] : 0;
    s[threadIdx.x] = v;
    __syncthreads();
    for (int off = 1; off < SCAN_B; off <<= 1) {
        int t = (threadIdx.x >= off) ? s[threadIdx.x - off] : 0;
        __syncthreads();
        s[threadIdx.x] += t;
        __syncthreads();
    }
    if (threadIdx.x < nb) blk[threadIdx.x] = s[threadIdx.x] - v;  // exclusive
}

__global__ void scan_final_kernel(const int* __restrict__ deg, const int* __restrict__ blk,
                                  int* __restrict__ row_start, int* __restrict__ cursor, int n) {
    __shared__ int s[SCAN_B];
    int i = blockIdx.x * SCAN_B + threadIdx.x;
    int v = (i < n) ? deg[i] : 0;
    s[threadIdx.x] = v;
    __syncthreads();
    for (int off = 1; off < SCAN_B; off <<= 1) {
        int t = (threadIdx.x >= off) ? s[threadIdx.x - off] : 0;
        __syncthreads();
        s[threadIdx.x] += t;
        __syncthreads();
    }
    if (i < n) {
        int excl = s[threadIdx.x] - v + blk[blockIdx.x];
        row_start[i] = excl;
        cursor[i]    = excl;
    }
}

__global__ void fill_csr_kernel(const int* __restrict__ row, const int* __restrict__ col,
                                int* __restrict__ cursor, int* __restrict__ cols,
                                int e, int n) {
    int i = blockIdx.x * blockDim.x + threadIdx.x;
    if (i < e) {
        int r = row[i];
        if ((unsigned)r < (unsigned)n) {
            int c = col[i];
            if ((unsigned)c >= (unsigned)n) c = 0;
            int p = atomicAdd(&cursor[r], 1);
            cols[p] = c;
        }
    }
}

// ---------------- weight repacks ----------------

__global__ void prep_all_kernel(
    const float* __restrict__ W_ih, const float* __restrict__ W_hh,
    const float* __restrict__ b_ih, const float* __restrict__ b_hh,
    const float* __restrict__ W_in, const float* __restrict__ b_in,
    const float* __restrict__ W_t1, const float* __restrict__ b_t1,
    const float* __restrict__ W_out,
    float* __restrict__ W2p, float* __restrict__ B2,
    float* __restrict__ W1p, float* __restrict__ B1,
    float* __restrict__ Wop) {
    int j = threadIdx.x;  // 256 threads, 1 block
    {
        float b;
        if (j < 128)      b = b_ih[j] + b_hh[j];
        else if (j < 192) b = b_ih[j];
        else              b = b_hh[j - 64];
        B2[j] = b;
        for (int k = 0; k < KDIM; k++) {
            float v;
            if (j < 128)      v = (k < 64) ? W_ih[j * 64 + k] : W_hh[j * 64 + (k - 64)];
            else if (j < 192) v = (k < 64) ? W_ih[j * 64 + k] : 0.f;
            else              v = (k >= 64) ? W_hh[(j - 64) * 64 + (k - 64)] : 0.f;
            W2p[(size_t)(k >> 4) * (JOUT * 16) + j * 16 + (k & 15)] = v;
        }
    }
    if (j < 128) {
        B1[j] = (j < 64) ? b_in[j] : b_t1[j - 64];
        const float* src = (j < 64) ? (W_in + (size_t)j * IN_DIM)
                                    : (W_t1 + (size_t)(j - 64) * IN_DIM);
        for (int k = 0; k < IN_DIM; k++)
            W1p[(size_t)(k >> 4) * (128 * 16) + j * 16 + (k & 15)] = src[k];
    }
    if (j < 64) {
        for (int k = 0; k < HID; k++)
            Wop[(size_t)(k >> 4) * (64 * 16) + j * 16 + (k & 15)] = W_out[(size_t)j * HID + k];
    }
}

// ---------------- init as tiled GEMM: h0 + tau (round-9 version, proven neutral) ----------------

__global__ __launch_bounds__(256, 3) void init_gemm_kernel(
    const float* __restrict__ x, const float* __restrict__ W1p,
    const float* __restrict__ B1,
    const float* __restrict__ W_t2, const float* __restrict__ b_t2,
    float* __restrict__ X1, float* __restrict__ tau, int n) {
    __shared__ float xs[NT * XS_STRIDE];     // 33 KB; reused as t1s [NT][65]
    __shared__ float wsh[128 * WS_STRIDE];   // 10 KB

    const int t  = threadIdx.x;
    const int tx = t & 15;
    const int ty = t >> 4;
    const int node0 = blockIdx.x * NT;

#pragma unroll
    for (int i = 0; i < 8; i++) {
        int f4 = i * 256 + t;
        int r  = f4 >> 5;
        int c4 = f4 & 31;
        float4 v = make_float4(0.f, 0.f, 0.f, 0.f);
        int node = node0 + r;
        if (node < n) v = *(const float4*)(x + (size_t)node * IN_DIM + c4 * 4);
        *(float4*)(xs + r * XS_STRIDE + c4 * 4) = v;
    }

    float acc[4][2][4];  // [nd][gb][i]; j = gb*64 + i*16 + tx
#pragma unroll
    for (int gb = 0; gb < 2; gb++)
#pragma unroll
        for (int i = 0; i < 4; i++) {
            float b = B1[gb * 64 + i * 16 + tx];
#pragma unroll
            for (int nd = 0; nd < 4; nd++) acc[nd][gb][i] = b;
        }

    const float* wbase = wsh + tx * WS_STRIDE;
#pragma unroll 1
    for (int kc = 0; kc < 8; kc++) {
        __syncthreads();
        {
            const float4* src = (const float4*)(W1p + (size_t)kc * (128 * 16));
#pragma unroll
            for (int i = 0; i < 2; i++) {
                int f4  = i * 256 + t;
                int row = f4 >> 2;
                int k4  = f4 & 3;
                *(float4*)(wsh + row * WS_STRIDE + k4 * 4) = src[f4];
            }
        }
        __syncthreads();
        const float* xbase = xs + (ty * 4) * XS_STRIDE + kc * 16;
#pragma unroll
        for (int k4 = 0; k4 < 4; k4++) {
            float4 xv[4];
#pragma unroll
            for (int nd = 0; nd < 4; nd++)
                xv[nd] = *(const float4*)(xbase + nd * XS_STRIDE + k4 * 4);
#pragma unroll
            for (int gb = 0; gb < 2; gb++)
#pragma unroll
                for (int i = 0; i < 4; i++) {
                    float4 w = *(const float4*)(wbase + (gb * 64 + i * 16) * WS_STRIDE + k4 * 4);
#pragma unroll
                    for (int nd = 0; nd < 4; nd++) {
                        acc[nd][gb][i] += w.x * xv[nd].x + w.y * xv[nd].y
                                        + w.z * xv[nd].z + w.w * xv[nd].w;
                    }
                }
        }
    }

    // xs is dead; reuse as t1s [NT][65]
    __syncthreads();
    float* t1s = xs;
#pragma unroll
    for (int nd = 0; nd < 4; nd++) {
        int r = ty * 4 + nd;
        int node = node0 + r;
#pragma unroll
        for (int i = 0; i < 4; i++) {
            float h0 = fmaxf(acc[nd][0][i], 0.f);
            float t1 = fmaxf(acc[nd][1][i], 0.f);
            if (node < n) X1[(size_t)node * KDIM + 64 + i * 16 + tx] = h0;
            t1s[r * 65 + i * 16 + tx] = t1;
        }
    }
    __syncthreads();

    if (t < NT) {
        int node = node0 + t;
        if (node < n) {
            float tsum = 0.f;
#pragma unroll 1
            for (int m = 0; m < TAU_DIM; m++) {
                float a = b_t2[m];
                const float* wr = W_t2 + (size_t)m * HID;
#pragma unroll
                for (int k = 0; k < HID; k++) a += wr[k] * t1s[t * 65 + k];
                tsum += 1.f / (1.f + expf(-a));
            }
            tau[node] = tsum * (1.f / TAU_DIM);
        }
    }
}

// ---------------- aggregate: X1[v][aoff..] = tau[v] * sum |h[v]-h[col]| ----------------

__global__ __launch_bounds__(256) void aggregate_kernel(
    float* __restrict__ X1, const float* __restrict__ tau,
    const int* __restrict__ row_start, const int* __restrict__ deg,
    const int* __restrict__ cols, int n, int hoff, int aoff) {
    int t = blockIdx.x * blockDim.x + threadIdx.x;
    int v = t >> 4;
    if (v >= n) return;
    int c4 = (t & 15) * 4;

    float4 hv = *(const float4*)(X1 + (size_t)v * KDIM + hoff + c4);
    float4 s0 = make_float4(0.f, 0.f, 0.f, 0.f);
    float4 s1 = make_float4(0.f, 0.f, 0.f, 0.f);
    int st = row_start[v];
    int d  = deg[v];
    int i = 0;
    for (; i + 1 < d; i += 2) {
        int c0 = cols[st + i];
        int c1 = cols[st + i + 1];
        float4 hc0 = *(const float4*)(X1 + (size_t)c0 * KDIM + hoff + c4);
        float4 hc1 = *(const float4*)(X1 + (size_t)c1 * KDIM + hoff + c4);
        s0.x += fabsf(hv.x - hc0.x);
        s0.y += fabsf(hv.y - hc0.y);
        s0.z += fabsf(hv.z - hc0.z);
        s0.w += fabsf(hv.w - hc0.w);
        s1.x += fabsf(hv.x - hc1.x);
        s1.y += fabsf(hv.y - hc1.y);
        s1.z += fabsf(hv.z - hc1.z);
        s1.w += fabsf(hv.w - hc1.w);
    }
    if (i < d) {
        int c = cols[st + i];
        float4 hc = *(const float4*)(X1 + (size_t)c * KDIM + hoff + c4);
        s0.x += fabsf(hv.x - hc.x);
        s0.y += fabsf(hv.y - hc.y);
        s0.z += fabsf(hv.z - hc.z);
        s0.w += fabsf(hv.w - hc.w);
    }
    float tv = tau[v];
    *(float4*)(X1 + (size_t)v * KDIM + aoff + c4) =
        make_float4((s0.x + s1.x) * tv, (s0.y + s1.y) * tv,
                    (s0.z + s1.z) * tv, (s0.w + s1.w) * tv);
}

// ---------------- GRU as tiled GEMM + fused gating ----------------
// ROUND-8 BODY (proven, no spill) + double-buffered W staging (T14 pattern):
// issue kc+1's 4 global dwordx4 loads BEFORE the k4 compute (latency hides
// under ~2048 cy of FMA), ds_write to the other buffer after, ONE barrier
// per kc. NO launch_bounds min-waves, NO k4 unroll (round-9 post-mortem:
// that combination spill-cascaded to 6 GB of scratch traffic).

__global__ __launch_bounds__(256) void gru_gemm_kernel(
    float* __restrict__ X1, const float* __restrict__ W2p,
    const float* __restrict__ B2, int n, int hoff, int aoff) {
    __shared__ float xs[NT * XS_STRIDE];        // 33 KB
    __shared__ float wsh[2][JOUT * WS_STRIDE];  // 40 KB (double buffer)

    const int t  = threadIdx.x;
    const int tx = t & 15;
    const int ty = t >> 4;
    const int node0 = blockIdx.x * NT;
    const int wrow = t >> 2;   // W-stage dest row (per 64-row chunk)
    const int wk4  = t & 3;    // W-stage dest k4

    // stage X tile
    {
        const int aoff4 = aoff >> 2, hoff4 = hoff >> 2;
#pragma unroll
        for (int i = 0; i < 8; i++) {
            int f4 = i * 256 + t;
            int r  = f4 >> 5;
            int c4 = f4 & 31;
            int src4 = (c4 < 16) ? (aoff4 + c4) : (hoff4 + (c4 - 16));
            float4 v = make_float4(0.f, 0.f, 0.f, 0.f);
            int node = node0 + r;
            if (node < n) v = *(const float4*)(X1 + (size_t)node * KDIM + src4 * 4);
            *(float4*)(xs + r * XS_STRIDE + c4 * 4) = v;
        }
    }
    // stage W chunk 0 into buffer 0
    {
        const float4* src = (const float4*)(W2p);
        *(float4*)(&wsh[0][(0   + wrow) * WS_STRIDE + wk4 * 4]) = src[t];
        *(float4*)(&wsh[0][(64  + wrow) * WS_STRIDE + wk4 * 4]) = src[256 + t];
        *(float4*)(&wsh[0][(128 + wrow) * WS_STRIDE + wk4 * 4]) = src[512 + t];
        *(float4*)(&wsh[0][(192 + wrow) * WS_STRIDE + wk4 * 4]) = src[768 + t];
    }

    float acc[4][4][4];  // [nd][gate-quad][i]; j = gb*64 + i*16 + tx
#pragma unroll
    for (int gb = 0; gb < 4; gb++)
#pragma unroll
        for (int i = 0; i < 4; i++) {
            float b = B2[gb * 64 + i * 16 + tx];
#pragma unroll
            for (int nd = 0; nd < 4; nd++) acc[nd][gb][i] = b;
        }

    __syncthreads();  // xs + wsh[0] ready

#pragma unroll 1
    for (int kc = 0; kc < 8; kc++) {
        const int cur = kc & 1;
        // issue next chunk's global loads early (hidden under compute)
        float4 wr0, wr1, wr2, wr3;
        if (kc < 7) {
            const float4* src = (const float4*)(W2p + (size_t)(kc + 1) * (JOUT * 16));
            wr0 = src[t];
            wr1 = src[256 + t];
            wr2 = src[512 + t];
            wr3 = src[768 + t];
        }
#pragma unroll 1
        for (int k4 = 0; k4 < 4; k4++) {
            float4 xv[4];
#pragma unroll
            for (int nd = 0; nd < 4; nd++)
                xv[nd] = *(const float4*)(xs + (ty * 4 + nd) * XS_STRIDE + kc * 16 + k4 * 4);
#pragma unroll
            for (int gb = 0; gb < 4; gb++)
#pragma unroll
                for (int i = 0; i < 4; i++) {
                    float4 w = *(const float4*)(&wsh[cur][(gb * 64 + i * 16 + tx) * WS_STRIDE + k4 * 4]);
#pragma unroll
                    for (int nd = 0; nd < 4; nd++) {
                        acc[nd][gb][i] += w.x * xv[nd].x + w.y * xv[nd].y
                                        + w.z * xv[nd].z + w.w * xv[nd].w;
                    }
                }
        }
        if (kc < 7) {
            // write-late into the other buffer (readers of wsh[cur] unaffected)
            float* wnxt = &wsh[cur ^ 1][0];
            *(float4*)(&wnxt[(0   + wrow) * WS_STRIDE + wk4 * 4]) = wr0;
            *(float4*)(&wnxt[(64  + wrow) * WS_STRIDE + wk4 * 4]) = wr1;
            *(float4*)(&wnxt[(128 + wrow) * WS_STRIDE + wk4 * 4]) = wr2;
            *(float4*)(&wnxt[(192 + wrow) * WS_STRIDE + wk4 * 4]) = wr3;
        }
        __syncthreads();  // single barrier per kc
    }

#pragma unroll
    for (int nd = 0; nd < 4; nd++) {
        int node = node0 + ty * 4 + nd;
        if (node < n) {
#pragma unroll
            for (int i = 0; i < 4; i++) {
                float r  = 1.f / (1.f + expf(-acc[nd][0][i]));
                float z  = 1.f / (1.f + expf(-acc[nd][1][i]));
                float nn = tanhf(acc[nd][2][i] + r * acc[nd][3][i]);
                float hold = xs[(ty * 4 + nd) * XS_STRIDE + 64 + i * 16 + tx];
                X1[(size_t)node * KDIM + aoff + i * 16 + tx] = (1.f - z) * nn + z * hold;
            }
        }
    }
}

// ---------------- output projection as tiled GEMM (round-9 version, proven neutral) ----------------

__global__ __launch_bounds__(256) void out_gemm_kernel(
    const float* __restrict__ X1, const float* __restrict__ Wop,
    const float* __restrict__ b_out, float* __restrict__ out, int n, int hoff) {
    __shared__ float xs[NT * 68];          // 17.4 KB (64 + 4 pad)
    __shared__ float wsh[64 * WS_STRIDE];  // 5 KB

    const int t  = threadIdx.x;
    const int tx = t & 15;
    const int ty = t >> 4;
    const int node0 = blockIdx.x * NT;

#pragma unroll
    for (int i = 0; i < 4; i++) {
        int f4 = i * 256 + t;
        int r  = f4 >> 4;
        int c4 = f4 & 15;
        float4 v = make_float4(0.f, 0.f, 0.f, 0.f);
        int node = node0 + r;
        if (node < n) v = *(const float4*)(X1 + (size_t)node * KDIM + hoff + c4 * 4);
        *(float4*)(xs + r * 68 + c4 * 4) = v;
    }

    float acc[4][4];  // [nd][i]; j = i*16 + tx
#pragma unroll
    for (int i = 0; i < 4; i++) {
        float b = b_out[i * 16 + tx];
#pragma unroll
        for (int nd = 0; nd < 4; nd++) acc[nd][i] = b;
    }

    const float* wbase = wsh + tx * WS_STRIDE;
#pragma unroll 1
    for (int kc = 0; kc < 4; kc++) {
        __syncthreads();
        {
            const float4* src = (const float4*)(Wop + (size_t)kc * (64 * 16));
            int f4  = t;
            int row = f4 >> 2;
            int k4  = f4 & 3;
            *(float4*)(wsh + row * WS_STRIDE + k4 * 4) = src[f4];
        }
        __syncthreads();
        const float* xbase = xs + (ty * 4) * 68 + kc * 16;
#pragma unroll
        for (int k4 = 0; k4 < 4; k4++) {
            float4 xv[4];
#pragma unroll
            for (int nd = 0; nd < 4; nd++)
                xv[nd] = *(const float4*)(xbase + nd * 68 + k4 * 4);
#pragma unroll
            for (int i = 0; i < 4; i++) {
                float4 w = *(const float4*)(wbase + (i * 16) * WS_STRIDE + k4 * 4);
#pragma unroll
                for (int nd = 0; nd < 4; nd++) {
                    acc[nd][i] += w.x * xv[nd].x + w.y * xv[nd].y
                                + w.z * xv[nd].z + w.w * xv[nd].w;
                }
            }
        }
    }

#pragma unroll
    for (int nd = 0; nd < 4; nd++) {
        int node = node0 + ty * 4 + nd;
        if (node < n) {
#pragma unroll
            for (int i = 0; i < 4; i++)
                out[(size_t)node * HID + i * 16 + tx] = acc[nd][i];
        }
    }
}

// ---------------- launch ----------------

extern "C" void kernel_launch(void* const* d_in, const int* in_sizes, int n_in,
                              void* d_out, int out_size, void* d_ws, size_t ws_size,
                              hipStream_t stream) {
    const float* x     = (const float*)d_in[0];
    const int*   ei    = (const int*)d_in[1];
    const float* W_in  = (const float*)d_in[2];
    const float* b_in  = (const float*)d_in[3];
    const float* W_t1  = (const float*)d_in[4];
    const float* b_t1  = (const float*)d_in[5];
    const float* W_t2  = (const float*)d_in[6];
    const float* b_t2  = (const float*)d_in[7];
    const float* W_ih  = (const float*)d_in[8];
    const float* b_ih  = (const float*)d_in[9];
    const float* W_hh  = (const float*)d_in[10];
    const float* b_hh  = (const float*)d_in[11];
    const float* W_out = (const float*)d_in[12];
    const float* b_out = (const float*)d_in[13];
    float* out = (float*)d_out;

    const int n = in_sizes[0] / IN_DIM;  // 100000
    const int e = in_sizes[1] / 2;       // 1000000
    const int* row = ei;
    const int* col = ei + e;

    char* ws = (char*)d_ws;
    float* X1  = (float*)ws;  ws += (size_t)n * KDIM * sizeof(float);   // 51.2 MB
    float* W2p = (float*)ws;  ws += (size_t)JOUT * KDIM * sizeof(float);
    float* B2  = (float*)ws;  ws += JOUT * sizeof(float);
    float* W1p = (float*)ws;  ws += (size_t)128 * IN_DIM * sizeof(float);
    float* B1  = (float*)ws;  ws += 128 * sizeof(float);
    float* Wop = (float*)ws;  ws += (size_t)64 * HID * sizeof(float);
    float* tau = (float*)ws;  ws += (size_t)n * sizeof(float);
    int* deg       = (int*)ws;  ws += (size_t)n * sizeof(int);
    int* row_start = (int*)ws;  ws += (size_t)n * sizeof(int);
    int* cursor    = (int*)ws;  ws += (size_t)n * sizeof(int);
    int* blk       = (int*)ws;  ws += SCAN_B * sizeof(int);
    int* cols      = (int*)ws;  ws += (size_t)e * sizeof(int);

    const int nb = (n + SCAN_B - 1) / SCAN_B;
    const int ngemm = (n + NT - 1) / NT;

    zero_int_kernel<<<(n + 255) / 256, 256, 0, stream>>>(deg, n);
    count_deg_kernel<<<(e + 255) / 256, 256, 0, stream>>>(row, deg, e, n);
    block_sum_kernel<<<nb, SCAN_B, 0, stream>>>(deg, blk, n);
    scan_blk_kernel<<<1, SCAN_B, 0, stream>>>(blk, nb);
    scan_final_kernel<<<nb, SCAN_B, 0, stream>>>(deg, blk, row_start, cursor, n);
    fill_csr_kernel<<<(e + 255) / 256, 256, 0, stream>>>(row, col, cursor, cols, e, n);

    prep_all_kernel<<<1, 256, 0, stream>>>(W_ih, W_hh, b_ih, b_hh,
                                           W_in, b_in, W_t1, b_t1, W_out,
                                           W2p, B2, W1p, B1, Wop);
    init_gemm_kernel<<<ngemm, 256, 0, stream>>>(x, W1p, B1, W_t2, b_t2, X1, tau, n);

    int hoff = 64, aoff = 0;  // h starts in cols [64,128)
    for (int it = 0; it < 5; ++it) {
        aggregate_kernel<<<((n * 16) + 255) / 256, 256, 0, stream>>>(
            X1, tau, row_start, deg, cols, n, hoff, aoff);
        gru_gemm_kernel<<<ngemm, 256, 0, stream>>>(X1, W2p, B2, n, hoff, aoff);
        int tmp = hoff; hoff = aoff; aoff = tmp;  // h' now lives where agg was
    }
    out_gemm_kernel<<<ngemm, 256, 0, stream>>>(X1, Wop, b_out, out, n, hoff);
}

// Round 11
// 1003.913 us; speedup vs baseline: 8.5220x; 1.6510x over previous
//
#include <hip/hip_runtime.h>

#define HID 64
#define IN_DIM 128
#define TAU_DIM 8
#define SCAN_B 1024

#define KDIM 128        // X row = [agg(64) | h(64)]
#define NT 64           // nodes per GEMM block
#define JOUT 256        // padded gate outputs: [r(64) z(64) | i_n(64) | h_n(64)]
#define XS_STRIDE 132   // 128 + 4 pad (f32 words)
#define WS_STRIDE 20    // 16 + 4 pad (f32 words)

typedef short bf16x8 __attribute__((ext_vector_type(8)));   // 8 bf16 = 4 VGPR
typedef float f32x4 __attribute__((ext_vector_type(4)));

__device__ __forceinline__ unsigned short f2bf(float f) {
    union { float f; unsigned u; } v; v.f = f;
    unsigned r = v.u + 0x7FFF + ((v.u >> 16) & 1);  // RNE
    return (unsigned short)(r >> 16);
}

// ---------------- CSR build (bounds-guarded) ----------------

__global__ void zero_int_kernel(int* __restrict__ p, int n) {
    int i = blockIdx.x * blockDim.x + threadIdx.x;
    if (i < n) p[i] = 0;
}

__global__ void count_deg_kernel(const int* __restrict__ row, int* __restrict__ deg,
                                 int e, int n) {
    int i = blockIdx.x * blockDim.x + threadIdx.x;
    if (i < e) {
        int r = row[i];
        if ((unsigned)r < (unsigned)n) atomicAdd(&deg[r], 1);
    }
}

__global__ void block_sum_kernel(const int* __restrict__ deg, int* __restrict__ blk, int n) {
    __shared__ int s[SCAN_B];
    int i = blockIdx.x * SCAN_B + threadIdx.x;
    s[threadIdx.x] = (i < n) ? deg[i] : 0;
    __syncthreads();
    for (int off = SCAN_B / 2; off > 0; off >>= 1) {
        if (threadIdx.x < off) s[threadIdx.x] += s[threadIdx.x + off];
        __syncthreads();
    }
    if (threadIdx.x == 0) blk[blockIdx.x] = s[0];
}

__global__ void scan_blk_kernel(int* __restrict__ blk, int nb) {
    __shared__ int s[SCAN_B];
    int v = (threadIdx.x < nb) ? blk[threadIdx.x] : 0;
    s[threadIdx.x] = v;
    __syncthreads();
    for (int off = 1; off < SCAN_B; off <<= 1) {
        int t = (threadIdx.x >= off) ? s[threadIdx.x - off] : 0;
        __syncthreads();
        s[threadIdx.x] += t;
        __syncthreads();
    }
    if (threadIdx.x < nb) blk[threadIdx.x] = s[threadIdx.x] - v;  // exclusive
}

__global__ void scan_final_kernel(const int* __restrict__ deg, const int* __restrict__ blk,
                                  int* __restrict__ row_start, int* __restrict__ cursor, int n) {
    __shared__ int s[SCAN_B];
    int i = blockIdx.x * SCAN_B + threadIdx.x;
    int v = (i < n) ? deg[i] : 0;
    s[threadIdx.x] = v;
    __syncthreads();
    for (int off = 1; off < SCAN_B; off <<= 1) {
        int t = (threadIdx.x >= off) ? s[threadIdx.x - off] : 0;
        __syncthreads();
        s[threadIdx.x] += t;
        __syncthreads();
    }
    if (i < n) {
        int excl = s[threadIdx.x] - v + blk[blockIdx.x];
        row_start[i] = excl;
        cursor[i]    = excl;
    }
}

__global__ void fill_csr_kernel(const int* __restrict__ row, const int* __restrict__ col,
                                int* __restrict__ cursor, int* __restrict__ cols,
                                int e, int n) {
    int i = blockIdx.x * blockDim.x + threadIdx.x;
    if (i < e) {
        int r = row[i];
        if ((unsigned)r < (unsigned)n) {
            int c = col[i];
            if ((unsigned)c >= (unsigned)n) c = 0;
            int p = atomicAdd(&cursor[r], 1);
            cols[p] = c;
        }
    }
}

// ---------------- weight repacks ----------------
// W2bf [256][128] bf16 row-major: GRU gate matrix for MFMA B-frags.
//   rows 0..127:  [W_ih[j] | W_hh[j]]  (r,z: pre-activations sum)
//   rows 128..191:[W_ih_n | 0] ; rows 192..255:[0 | W_hh_n]
// W1p [8][128][16] f32: init GEMM. Wop [4][64][16] f32: out projection.

__global__ void prep_all_kernel(
    const float* __restrict__ W_ih, const float* __restrict__ W_hh,
    const float* __restrict__ b_ih, const float* __restrict__ b_hh,
    const float* __restrict__ W_in, const float* __restrict__ b_in,
    const float* __restrict__ W_t1, const float* __restrict__ b_t1,
    const float* __restrict__ W_out,
    unsigned short* __restrict__ W2bf, float* __restrict__ B2,
    float* __restrict__ W1p, float* __restrict__ B1,
    float* __restrict__ Wop) {
    int j = threadIdx.x;  // 256 threads, 1 block
    {
        float b;
        if (j < 128)      b = b_ih[j] + b_hh[j];
        else if (j < 192) b = b_ih[j];
        else              b = b_hh[j - 64];
        B2[j] = b;
        for (int k = 0; k < KDIM; k++) {
            float v;
            if (j < 128)      v = (k < 64) ? W_ih[j * 64 + k] : W_hh[j * 64 + (k - 64)];
            else if (j < 192) v = (k < 64) ? W_ih[j * 64 + k] : 0.f;
            else              v = (k >= 64) ? W_hh[(j - 64) * 64 + (k - 64)] : 0.f;
            W2bf[(size_t)j * KDIM + k] = f2bf(v);
        }
    }
    if (j < 128) {
        B1[j] = (j < 64) ? b_in[j] : b_t1[j - 64];
        const float* src = (j < 64) ? (W_in + (size_t)j * IN_DIM)
                                    : (W_t1 + (size_t)(j - 64) * IN_DIM);
        for (int k = 0; k < IN_DIM; k++)
            W1p[(size_t)(k >> 4) * (128 * 16) + j * 16 + (k & 15)] = src[k];
    }
    if (j < 64) {
        for (int k = 0; k < HID; k++)
            Wop[(size_t)(k >> 4) * (64 * 16) + j * 16 + (k & 15)] = W_out[(size_t)j * HID + k];
    }
}

// ---------------- init as tiled GEMM: h0 + tau (round-9 version, proven) ----------------

__global__ __launch_bounds__(256, 3) void init_gemm_kernel(
    const float* __restrict__ x, const float* __restrict__ W1p,
    const float* __restrict__ B1,
    const float* __restrict__ W_t2, const float* __restrict__ b_t2,
    float* __restrict__ X1, float* __restrict__ tau, int n) {
    __shared__ float xs[NT * XS_STRIDE];     // 33 KB; reused as t1s [NT][65]
    __shared__ float wsh[128 * WS_STRIDE];   // 10 KB

    const int t  = threadIdx.x;
    const int tx = t & 15;
    const int ty = t >> 4;
    const int node0 = blockIdx.x * NT;

#pragma unroll
    for (int i = 0; i < 8; i++) {
        int f4 = i * 256 + t;
        int r  = f4 >> 5;
        int c4 = f4 & 31;
        float4 v = make_float4(0.f, 0.f, 0.f, 0.f);
        int node = node0 + r;
        if (node < n) v = *(const float4*)(x + (size_t)node * IN_DIM + c4 * 4);
        *(float4*)(xs + r * XS_STRIDE + c4 * 4) = v;
    }

    float acc[4][2][4];
#pragma unroll
    for (int gb = 0; gb < 2; gb++)
#pragma unroll
        for (int i = 0; i < 4; i++) {
            float b = B1[gb * 64 + i * 16 + tx];
#pragma unroll
            for (int nd = 0; nd < 4; nd++) acc[nd][gb][i] = b;
        }

    const float* wbase = wsh + tx * WS_STRIDE;
#pragma unroll 1
    for (int kc = 0; kc < 8; kc++) {
        __syncthreads();
        {
            const float4* src = (const float4*)(W1p + (size_t)kc * (128 * 16));
#pragma unroll
            for (int i = 0; i < 2; i++) {
                int f4  = i * 256 + t;
                int row = f4 >> 2;
                int k4  = f4 & 3;
                *(float4*)(wsh + row * WS_STRIDE + k4 * 4) = src[f4];
            }
        }
        __syncthreads();
        const float* xbase = xs + (ty * 4) * XS_STRIDE + kc * 16;
#pragma unroll
        for (int k4 = 0; k4 < 4; k4++) {
            float4 xv[4];
#pragma unroll
            for (int nd = 0; nd < 4; nd++)
                xv[nd] = *(const float4*)(xbase + nd * XS_STRIDE + k4 * 4);
#pragma unroll
            for (int gb = 0; gb < 2; gb++)
#pragma unroll
                for (int i = 0; i < 4; i++) {
                    float4 w = *(const float4*)(wbase + (gb * 64 + i * 16) * WS_STRIDE + k4 * 4);
#pragma unroll
                    for (int nd = 0; nd < 4; nd++) {
                        acc[nd][gb][i] += w.x * xv[nd].x + w.y * xv[nd].y
                                        + w.z * xv[nd].z + w.w * xv[nd].w;
                    }
                }
        }
    }

    __syncthreads();
    float* t1s = xs;  // xs dead; reuse as t1s [NT][65]
#pragma unroll
    for (int nd = 0; nd < 4; nd++) {
        int r = ty * 4 + nd;
        int node = node0 + r;
#pragma unroll
        for (int i = 0; i < 4; i++) {
            float h0 = fmaxf(acc[nd][0][i], 0.f);
            float t1 = fmaxf(acc[nd][1][i], 0.f);
            if (node < n) X1[(size_t)node * KDIM + 64 + i * 16 + tx] = h0;
            t1s[r * 65 + i * 16 + tx] = t1;
        }
    }
    __syncthreads();

    if (t < NT) {
        int node = node0 + t;
        if (node < n) {
            float tsum = 0.f;
#pragma unroll 1
            for (int m = 0; m < TAU_DIM; m++) {
                float a = b_t2[m];
                const float* wr = W_t2 + (size_t)m * HID;
#pragma unroll
                for (int k = 0; k < HID; k++) a += wr[k] * t1s[t * 65 + k];
                tsum += 1.f / (1.f + expf(-a));
            }
            tau[node] = tsum * (1.f / TAU_DIM);
        }
    }
}

// ---------------- aggregate: X1[v][aoff..] = tau[v] * sum |h[v]-h[col]| ----------------

__global__ __launch_bounds__(256) void aggregate_kernel(
    float* __restrict__ X1, const float* __restrict__ tau,
    const int* __restrict__ row_start, const int* __restrict__ deg,
    const int* __restrict__ cols, int n, int hoff, int aoff) {
    int t = blockIdx.x * blockDim.x + threadIdx.x;
    int v = t >> 4;
    if (v >= n) return;
    int c4 = (t & 15) * 4;

    float4 hv = *(const float4*)(X1 + (size_t)v * KDIM + hoff + c4);
    float4 s0 = make_float4(0.f, 0.f, 0.f, 0.f);
    float4 s1 = make_float4(0.f, 0.f, 0.f, 0.f);
    int st = row_start[v];
    int d  = deg[v];
    int i = 0;
    for (; i + 1 < d; i += 2) {
        int c0 = cols[st + i];
        int c1 = cols[st + i + 1];
        float4 hc0 = *(const float4*)(X1 + (size_t)c0 * KDIM + hoff + c4);
        float4 hc1 = *(const float4*)(X1 + (size_t)c1 * KDIM + hoff + c4);
        s0.x += fabsf(hv.x - hc0.x);
        s0.y += fabsf(hv.y - hc0.y);
        s0.z += fabsf(hv.z - hc0.z);
        s0.w += fabsf(hv.w - hc0.w);
        s1.x += fabsf(hv.x - hc1.x);
        s1.y += fabsf(hv.y - hc1.y);
        s1.z += fabsf(hv.z - hc1.z);
        s1.w += fabsf(hv.w - hc1.w);
    }
    if (i < d) {
        int c = cols[st + i];
        float4 hc = *(const float4*)(X1 + (size_t)c * KDIM + hoff + c4);
        s0.x += fabsf(hv.x - hc.x);
        s0.y += fabsf(hv.y - hc.y);
        s0.z += fabsf(hv.z - hc.z);
        s0.w += fabsf(hv.w - hc.w);
    }
    float tv = tau[v];
    *(float4*)(X1 + (size_t)v * KDIM + aoff + c4) =
        make_float4((s0.x + s1.x) * tv, (s0.y + s1.y) * tv,
                    (s0.z + s1.z) * tv, (s0.w + s1.w) * tv);
}

// ---------------- GRU via MFMA (bf16 inputs, fp32 accumulate/gating/state) ----------------
// LDS-free. Block = 4 waves x 16 nodes. Per wave: A-frags (its 16 nodes,
// K=128 as 4x bf16x8 per lane, converted from fp32 X1 once) persist in 16
// VGPRs; B-frags stream from L1/L2-hot 64 KB W2bf. mfma_f32_16x16x32_bf16;
// A: lane l -> X[node0+(l&15)][k=(l>>4)*8+j]; B: lane l -> W2[j0+(l&15)]
// [same k slice]; D: row=(l>>4)*4+r (node), col=l&15 (j)  [m89-verified].
// Gating fp32; h' written fp32 into the dead agg columns (ping-pong).
// If validation fails: revert to round-8 fp32 LDS body (179 us, proven).

__global__ __launch_bounds__(256) void gru_mfma_kernel(
    float* __restrict__ X1, const unsigned short* __restrict__ W2bf,
    const float* __restrict__ B2, int n, int hoff, int aoff) {
    const int t    = threadIdx.x;
    const int lane = t & 63;
    const int wave = t >> 6;
    const int col  = lane & 15;
    const int ksel = lane >> 4;  // 0..3
    const int nodebase = blockIdx.x * NT + wave * 16;

    // A-fragments: lane holds rows nodebase+col, k = kc*32 + ksel*8 .. +8
    bf16x8 afrag[4];
    {
        const int anode = nodebase + col;
#pragma unroll
        for (int kc = 0; kc < 4; kc++) {
            int c0 = ((kc < 2) ? (aoff + kc * 32) : (hoff + (kc - 2) * 32)) + ksel * 8;
            bf16x8 a;
            if (anode < n) {
                const float* p = X1 + (size_t)anode * KDIM + c0;
                float4 lo = *(const float4*)p;
                float4 hi = *(const float4*)(p + 4);
                a[0] = (short)f2bf(lo.x); a[1] = (short)f2bf(lo.y);
                a[2] = (short)f2bf(lo.z); a[3] = (short)f2bf(lo.w);
                a[4] = (short)f2bf(hi.x); a[5] = (short)f2bf(hi.y);
                a[6] = (short)f2bf(hi.z); a[7] = (short)f2bf(hi.w);
            } else {
                a[0] = 0; a[1] = 0; a[2] = 0; a[3] = 0;
                a[4] = 0; a[5] = 0; a[6] = 0; a[7] = 0;
            }
            afrag[kc] = a;
        }
    }

    const int onode_base = nodebase + ksel * 4;  // D rows of this lane

#pragma unroll 1
    for (int i = 0; i < 4; i++) {   // j-group: cols i*16..i*16+16 of each quad
        f32x4 acc[4];
#pragma unroll
        for (int gb = 0; gb < 4; gb++) {
            float b = B2[gb * 64 + i * 16 + col];
            f32x4 c; c[0] = b; c[1] = b; c[2] = b; c[3] = b;
#pragma unroll
            for (int kc = 0; kc < 4; kc++) {
                bf16x8 bf = *(const bf16x8*)(W2bf
                    + (size_t)(gb * 64 + i * 16 + col) * KDIM + kc * 32 + ksel * 8);
                c = __builtin_amdgcn_mfma_f32_16x16x32_bf16(afrag[kc], bf, c, 0, 0, 0);
            }
            acc[gb] = c;
        }
        // fused gating: r=sig(q0), z=sig(q1), n=tanh(q2 + r*q3)
#pragma unroll
        for (int r = 0; r < 4; r++) {
            int node = onode_base + r;
            if (node < n) {
                float rr = 1.f / (1.f + expf(-acc[0][r]));
                float z  = 1.f / (1.f + expf(-acc[1][r]));
                float nn = tanhf(acc[2][r] + rr * acc[3][r]);
                float hold = X1[(size_t)node * KDIM + hoff + i * 16 + col];
                X1[(size_t)node * KDIM + aoff + i * 16 + col] = (1.f - z) * nn + z * hold;
            }
        }
    }
}

// ---------------- output projection as tiled GEMM (round-9 version, proven) ----------------

__global__ __launch_bounds__(256) void out_gemm_kernel(
    const float* __restrict__ X1, const float* __restrict__ Wop,
    const float* __restrict__ b_out, float* __restrict__ out, int n, int hoff) {
    __shared__ float xs[NT * 68];          // 17.4 KB
    __shared__ float wsh[64 * WS_STRIDE];  // 5 KB

    const int t  = threadIdx.x;
    const int tx = t & 15;
    const int ty = t >> 4;
    const int node0 = blockIdx.x * NT;

#pragma unroll
    for (int i = 0; i < 4; i++) {
        int f4 = i * 256 + t;
        int r  = f4 >> 4;
        int c4 = f4 & 15;
        float4 v = make_float4(0.f, 0.f, 0.f, 0.f);
        int node = node0 + r;
        if (node < n) v = *(const float4*)(X1 + (size_t)node * KDIM + hoff + c4 * 4);
        *(float4*)(xs + r * 68 + c4 * 4) = v;
    }

    float acc[4][4];
#pragma unroll
    for (int i = 0; i < 4; i++) {
        float b = b_out[i * 16 + tx];
#pragma unroll
        for (int nd = 0; nd < 4; nd++) acc[nd][i] = b;
    }

    const float* wbase = wsh + tx * WS_STRIDE;
#pragma unroll 1
    for (int kc = 0; kc < 4; kc++) {
        __syncthreads();
        {
            const float4* src = (const float4*)(Wop + (size_t)kc * (64 * 16));
            int f4  = t;
            int row = f4 >> 2;
            int k4  = f4 & 3;
            *(float4*)(wsh + row * WS_STRIDE + k4 * 4) = src[f4];
        }
        __syncthreads();
        const float* xbase = xs + (ty * 4) * 68 + kc * 16;
#pragma unroll
        for (int k4 = 0; k4 < 4; k4++) {
            float4 xv[4];
#pragma unroll
            for (int nd = 0; nd < 4; nd++)
                xv[nd] = *(const float4*)(xbase + nd * 68 + k4 * 4);
#pragma unroll
            for (int i = 0; i < 4; i++) {
                float4 w = *(const float4*)(wbase + (i * 16) * WS_STRIDE + k4 * 4);
#pragma unroll
                for (int nd = 0; nd < 4; nd++) {
                    acc[nd][i] += w.x * xv[nd].x + w.y * xv[nd].y
                                + w.z * xv[nd].z + w.w * xv[nd].w;
                }
            }
        }
    }

#pragma unroll
    for (int nd = 0; nd < 4; nd++) {
        int node = node0 + ty * 4 + nd;
        if (node < n) {
#pragma unroll
            for (int i = 0; i < 4; i++)
                out[(size_t)node * HID + i * 16 + tx] = acc[nd][i];
        }
    }
}

// ---------------- launch ----------------

extern "C" void kernel_launch(void* const* d_in, const int* in_sizes, int n_in,
                              void* d_out, int out_size, void* d_ws, size_t ws_size,
                              hipStream_t stream) {
    const float* x     = (const float*)d_in[0];
    const int*   ei    = (const int*)d_in[1];
    const float* W_in  = (const float*)d_in[2];
    const float* b_in  = (const float*)d_in[3];
    const float* W_t1  = (const float*)d_in[4];
    const float* b_t1  = (const float*)d_in[5];
    const float* W_t2  = (const float*)d_in[6];
    const float* b_t2  = (const float*)d_in[7];
    const float* W_ih  = (const float*)d_in[8];
    const float* b_ih  = (const float*)d_in[9];
    const float* W_hh  = (const float*)d_in[10];
    const float* b_hh  = (const float*)d_in[11];
    const float* W_out = (const float*)d_in[12];
    const float* b_out = (const float*)d_in[13];
    float* out = (float*)d_out;

    const int n = in_sizes[0] / IN_DIM;  // 100000
    const int e = in_sizes[1] / 2;       // 1000000
    const int* row = ei;
    const int* col = ei + e;

    char* ws = (char*)d_ws;
    float* X1  = (float*)ws;  ws += (size_t)n * KDIM * sizeof(float);   // 51.2 MB
    unsigned short* W2bf = (unsigned short*)ws;  ws += (size_t)JOUT * KDIM * sizeof(unsigned short);
    float* B2  = (float*)ws;  ws += JOUT * sizeof(float);
    float* W1p = (float*)ws;  ws += (size_t)128 * IN_DIM * sizeof(float);
    float* B1  = (float*)ws;  ws += 128 * sizeof(float);
    float* Wop = (float*)ws;  ws += (size_t)64 * HID * sizeof(float);
    float* tau = (float*)ws;  ws += (size_t)n * sizeof(float);
    int* deg       = (int*)ws;  ws += (size_t)n * sizeof(int);
    int* row_start = (int*)ws;  ws += (size_t)n * sizeof(int);
    int* cursor    = (int*)ws;  ws += (size_t)n * sizeof(int);
    int* blk       = (int*)ws;  ws += SCAN_B * sizeof(int);
    int* cols      = (int*)ws;  ws += (size_t)e * sizeof(int);

    const int nb = (n + SCAN_B - 1) / SCAN_B;
    const int ngemm = (n + NT - 1) / NT;

    zero_int_kernel<<<(n + 255) / 256, 256, 0, stream>>>(deg, n);
    count_deg_kernel<<<(e + 255) / 256, 256, 0, stream>>>(row, deg, e, n);
    block_sum_kernel<<<nb, SCAN_B, 0, stream>>>(deg, blk, n);
    scan_blk_kernel<<<1, SCAN_B, 0, stream>>>(blk, nb);
    scan_final_kernel<<<nb, SCAN_B, 0, stream>>>(deg, blk, row_start, cursor, n);
    fill_csr_kernel<<<(e + 255) / 256, 256, 0, stream>>>(row, col, cursor, cols, e, n);

    prep_all_kernel<<<1, 256, 0, stream>>>(W_ih, W_hh, b_ih, b_hh,
                                           W_in, b_in, W_t1, b_t1, W_out,
                                           W2bf, B2, W1p, B1, Wop);
    init_gemm_kernel<<<ngemm, 256, 0, stream>>>(x, W1p, B1, W_t2, b_t2, X1, tau, n);

    int hoff = 64, aoff = 0;  // h starts in cols [64,128)
    for (int it = 0; it < 5; ++it) {
        aggregate_kernel<<<((n * 16) + 255) / 256, 256, 0, stream>>>(
            X1, tau, row_start, deg, cols, n, hoff, aoff);
        gru_mfma_kernel<<<ngemm, 256, 0, stream>>>(X1, W2bf, B2, n, hoff, aoff);
        int tmp = hoff; hoff = aoff; aoff = tmp;  // h' now lives where agg was
    }
    out_gemm_kernel<<<ngemm, 256, 0, stream>>>(X1, Wop, b_out, out, n, hoff);
}

// Round 13
// 879.727 us; speedup vs baseline: 9.7250x; 1.1412x over previous
//
#include <hip/hip_runtime.h>

#define HID 64
#define IN_DIM 128
#define TAU_DIM 8
#define SCAN_B 1024

#define KDIM 128        // X row = [agg(64) | h(64)]
#define NT 64           // nodes per GEMM block
#define JOUT 256        // padded gate outputs: [r(64) z(64) | i_n(64) | h_n(64)]
#define WS_STRIDE 20    // 16 + 4 pad (f32 words)

typedef short bf16x8 __attribute__((ext_vector_type(8)));   // 8 bf16 = 4 VGPR
typedef float f32x4 __attribute__((ext_vector_type(4)));

__device__ __forceinline__ unsigned short f2bf(float f) {
    union { float f; unsigned u; } v; v.f = f;
    unsigned r = v.u + 0x7FFF + ((v.u >> 16) & 1);  // RNE
    return (unsigned short)(r >> 16);
}

// ---------------- CSR build (bounds-guarded) ----------------

__global__ void zero_int_kernel(int* __restrict__ p, int n) {
    int i = blockIdx.x * blockDim.x + threadIdx.x;
    if (i < n) p[i] = 0;
}

__global__ void count_deg_kernel(const int* __restrict__ row, int* __restrict__ deg,
                                 int e, int n) {
    int i = blockIdx.x * blockDim.x + threadIdx.x;
    if (i < e) {
        int r = row[i];
        if ((unsigned)r < (unsigned)n) atomicAdd(&deg[r], 1);
    }
}

__global__ void block_sum_kernel(const int* __restrict__ deg, int* __restrict__ blk, int n) {
    __shared__ int s[SCAN_B];
    int i = blockIdx.x * SCAN_B + threadIdx.x;
    s[threadIdx.x] = (i < n) ? deg[i] : 0;
    __syncthreads();
    for (int off = SCAN_B / 2; off > 0; off >>= 1) {
        if (threadIdx.x < off) s[threadIdx.x] += s[threadIdx.x + off];
        __syncthreads();
    }
    if (threadIdx.x == 0) blk[blockIdx.x] = s[0];
}

__global__ void scan_blk_kernel(int* __restrict__ blk, int nb) {
    __shared__ int s[SCAN_B];
    int v = (threadIdx.x < nb) ? blk[threadIdx.x] : 0;
    s[threadIdx.x] = v;
    __syncthreads();
    for (int off = 1; off < SCAN_B; off <<= 1) {
        int t = (threadIdx.x >= off) ? s[threadIdx.x - off] : 0;
        __syncthreads();
        s[threadIdx.x] += t;
        __syncthreads();
    }
    if (threadIdx.x < nb) blk[threadIdx.x] = s[threadIdx.x] - v;  // exclusive
}

__global__ void scan_final_kernel(const int* __restrict__ deg, const int* __restrict__ blk,
                                  int* __restrict__ row_start, int* __restrict__ cursor, int n) {
    __shared__ int s[SCAN_B];
    int i = blockIdx.x * SCAN_B + threadIdx.x;
    int v = (i < n) ? deg[i] : 0;
    s[threadIdx.x] = v;
    __syncthreads();
    for (int off = 1; off < SCAN_B; off <<= 1) {
        int t = (threadIdx.x >= off) ? s[threadIdx.x - off] : 0;
        __syncthreads();
        s[threadIdx.x] += t;
        __syncthreads();
    }
    if (i < n) {
        int excl = s[threadIdx.x] - v + blk[blockIdx.x];
        row_start[i] = excl;
        cursor[i]    = excl;
    }
}

__global__ void fill_csr_kernel(const int* __restrict__ row, const int* __restrict__ col,
                                int* __restrict__ cursor, int* __restrict__ cols,
                                int e, int n) {
    int i = blockIdx.x * blockDim.x + threadIdx.x;
    if (i < e) {
        int r = row[i];
        if ((unsigned)r < (unsigned)n) {
            int c = col[i];
            if ((unsigned)c >= (unsigned)n) c = 0;
            int p = atomicAdd(&cursor[r], 1);
            cols[p] = c;
        }
    }
}

// ---------------- weight repacks ----------------
// W2bf [256][128] bf16: GRU gates (rows 0..127 [Wih|Whh] r,z summed;
//   128..191 [Wih_n|0]; 192..255 [0|Whh_n]); B2[256] f32.
// W1bf [128][128] bf16: init (rows 0..63 W_in, 64..127 W_t1); B1[128] f32.
// Wop [4][64][16] f32: out projection.

__global__ void prep_all_kernel(
    const float* __restrict__ W_ih, const float* __restrict__ W_hh,
    const float* __restrict__ b_ih, const float* __restrict__ b_hh,
    const float* __restrict__ W_in, const float* __restrict__ b_in,
    const float* __restrict__ W_t1, const float* __restrict__ b_t1,
    const float* __restrict__ W_out,
    unsigned short* __restrict__ W2bf, float* __restrict__ B2,
    unsigned short* __restrict__ W1bf, float* __restrict__ B1,
    float* __restrict__ Wop) {
    int j = threadIdx.x;  // 256 threads, 1 block
    {
        float b;
        if (j < 128)      b = b_ih[j] + b_hh[j];
        else if (j < 192) b = b_ih[j];
        else              b = b_hh[j - 64];
        B2[j] = b;
        for (int k = 0; k < KDIM; k++) {
            float v;
            if (j < 128)      v = (k < 64) ? W_ih[j * 64 + k] : W_hh[j * 64 + (k - 64)];
            else if (j < 192) v = (k < 64) ? W_ih[j * 64 + k] : 0.f;
            else              v = (k >= 64) ? W_hh[(j - 64) * 64 + (k - 64)] : 0.f;
            W2bf[(size_t)j * KDIM + k] = f2bf(v);
        }
    }
    if (j < 128) {
        B1[j] = (j < 64) ? b_in[j] : b_t1[j - 64];
        const float* src = (j < 64) ? (W_in + (size_t)j * IN_DIM)
                                    : (W_t1 + (size_t)(j - 64) * IN_DIM);
        for (int k = 0; k < IN_DIM; k++)
            W1bf[(size_t)j * IN_DIM + k] = f2bf(src[k]);
    }
    if (j < 64) {
        for (int k = 0; k < HID; k++)
            Wop[(size_t)(k >> 4) * (64 * 16) + j * 16 + (k & 15)] = W_out[(size_t)j * HID + k];
    }
}

// ---------------- init via MFMA: h0 + tau ----------------
// Same structure as the proven gru_mfma: block = 4 waves x 16 nodes, A-frags
// from x (fp32 -> bf16 in-register), B-frags from L1-hot 32 KB W1bf, no GEMM
// LDS/barriers. Outputs j<64: relu -> h0 (X1 cols [64,128)); j>=64: relu ->
// t1 in LDS, then 64 threads finish tau (fp32). D layout: col=lane&15,
// row=(lane>>4)*4+reg [m89-verified, confirmed working in gru_mfma].
// If validation fails: revert init to round-9 fp32 GEMM body (167 us, proven).

__global__ __launch_bounds__(256) void init_mfma_kernel(
    const float* __restrict__ x, const unsigned short* __restrict__ W1bf,
    const float* __restrict__ B1,
    const float* __restrict__ W_t2, const float* __restrict__ b_t2,
    float* __restrict__ X1, float* __restrict__ tau, int n) {
    __shared__ float t1s[NT * 65];  // 16.6 KB

    const int t    = threadIdx.x;
    const int lane = t & 63;
    const int wave = t >> 6;
    const int col  = lane & 15;
    const int ksel = lane >> 4;  // 0..3
    const int nodebase = blockIdx.x * NT + wave * 16;

    // A-fragments: lane holds row nodebase+col, k = kc*32 + ksel*8 .. +8
    bf16x8 afrag[4];
    {
        const int anode = nodebase + col;
#pragma unroll
        for (int kc = 0; kc < 4; kc++) {
            bf16x8 a;
            if (anode < n) {
                const float* p = x + (size_t)anode * IN_DIM + kc * 32 + ksel * 8;
                float4 lo = *(const float4*)p;
                float4 hi = *(const float4*)(p + 4);
                a[0] = (short)f2bf(lo.x); a[1] = (short)f2bf(lo.y);
                a[2] = (short)f2bf(lo.z); a[3] = (short)f2bf(lo.w);
                a[4] = (short)f2bf(hi.x); a[5] = (short)f2bf(hi.y);
                a[6] = (short)f2bf(hi.z); a[7] = (short)f2bf(hi.w);
            } else {
                a[0] = 0; a[1] = 0; a[2] = 0; a[3] = 0;
                a[4] = 0; a[5] = 0; a[6] = 0; a[7] = 0;
            }
            afrag[kc] = a;
        }
    }

#pragma unroll 1
    for (int i = 0; i < 8; i++) {   // j-group: cols i*16 .. i*16+16
        float b = B1[i * 16 + col];
        f32x4 c; c[0] = b; c[1] = b; c[2] = b; c[3] = b;
#pragma unroll
        for (int kc = 0; kc < 4; kc++) {
            bf16x8 bf = *(const bf16x8*)(W1bf
                + (size_t)(i * 16 + col) * IN_DIM + kc * 32 + ksel * 8);
            c = __builtin_amdgcn_mfma_f32_16x16x32_bf16(afrag[kc], bf, c, 0, 0, 0);
        }
#pragma unroll
        for (int r = 0; r < 4; r++) {
            int node = nodebase + ksel * 4 + r;
            float v = fmaxf(c[r], 0.f);
            if (i < 4) {
                if (node < n) X1[(size_t)node * KDIM + 64 + i * 16 + col] = v;
            } else {
                t1s[(wave * 16 + ksel * 4 + r) * 65 + (i - 4) * 16 + col] = v;
            }
        }
    }
    __syncthreads();

    if (t < NT) {
        int node = blockIdx.x * NT + t;
        if (node < n) {
            float tsum = 0.f;
#pragma unroll 1
            for (int m = 0; m < TAU_DIM; m++) {
                float a = b_t2[m];
                const float* wr = W_t2 + (size_t)m * HID;
#pragma unroll
                for (int k = 0; k < HID; k++) a += wr[k] * t1s[t * 65 + k];
                tsum += 1.f / (1.f + expf(-a));
            }
            tau[node] = tsum * (1.f / TAU_DIM);
        }
    }
}

// ---------------- aggregate: X1[v][aoff..] = tau[v] * sum |h[v]-h[col]| ----------------

__global__ __launch_bounds__(256) void aggregate_kernel(
    float* __restrict__ X1, const float* __restrict__ tau,
    const int* __restrict__ row_start, const int* __restrict__ deg,
    const int* __restrict__ cols, int n, int hoff, int aoff) {
    int t = blockIdx.x * blockDim.x + threadIdx.x;
    int v = t >> 4;
    if (v >= n) return;
    int c4 = (t & 15) * 4;

    float4 hv = *(const float4*)(X1 + (size_t)v * KDIM + hoff + c4);
    float4 s0 = make_float4(0.f, 0.f, 0.f, 0.f);
    float4 s1 = make_float4(0.f, 0.f, 0.f, 0.f);
    int st = row_start[v];
    int d  = deg[v];
    int i = 0;
    for (; i + 1 < d; i += 2) {
        int c0 = cols[st + i];
        int c1 = cols[st + i + 1];
        float4 hc0 = *(const float4*)(X1 + (size_t)c0 * KDIM + hoff + c4);
        float4 hc1 = *(const float4*)(X1 + (size_t)c1 * KDIM + hoff + c4);
        s0.x += fabsf(hv.x - hc0.x);
        s0.y += fabsf(hv.y - hc0.y);
        s0.z += fabsf(hv.z - hc0.z);
        s0.w += fabsf(hv.w - hc0.w);
        s1.x += fabsf(hv.x - hc1.x);
        s1.y += fabsf(hv.y - hc1.y);
        s1.z += fabsf(hv.z - hc1.z);
        s1.w += fabsf(hv.w - hc1.w);
    }
    if (i < d) {
        int c = cols[st + i];
        float4 hc = *(const float4*)(X1 + (size_t)c * KDIM + hoff + c4);
        s0.x += fabsf(hv.x - hc.x);
        s0.y += fabsf(hv.y - hc.y);
        s0.z += fabsf(hv.z - hc.z);
        s0.w += fabsf(hv.w - hc.w);
    }
    float tv = tau[v];
    *(float4*)(X1 + (size_t)v * KDIM + aoff + c4) =
        make_float4((s0.x + s1.x) * tv, (s0.y + s1.y) * tv,
                    (s0.z + s1.z) * tv, (s0.w + s1.w) * tv);
}

// ---------------- GRU via MFMA (round-11 proven) ----------------

__global__ __launch_bounds__(256) void gru_mfma_kernel(
    float* __restrict__ X1, const unsigned short* __restrict__ W2bf,
    const float* __restrict__ B2, int n, int hoff, int aoff) {
    const int t    = threadIdx.x;
    const int lane = t & 63;
    const int wave = t >> 6;
    const int col  = lane & 15;
    const int ksel = lane >> 4;  // 0..3
    const int nodebase = blockIdx.x * NT + wave * 16;

    bf16x8 afrag[4];
    {
        const int anode = nodebase + col;
#pragma unroll
        for (int kc = 0; kc < 4; kc++) {
            int c0 = ((kc < 2) ? (aoff + kc * 32) : (hoff + (kc - 2) * 32)) + ksel * 8;
            bf16x8 a;
            if (anode < n) {
                const float* p = X1 + (size_t)anode * KDIM + c0;
                float4 lo = *(const float4*)p;
                float4 hi = *(const float4*)(p + 4);
                a[0] = (short)f2bf(lo.x); a[1] = (short)f2bf(lo.y);
                a[2] = (short)f2bf(lo.z); a[3] = (short)f2bf(lo.w);
                a[4] = (short)f2bf(hi.x); a[5] = (short)f2bf(hi.y);
                a[6] = (short)f2bf(hi.z); a[7] = (short)f2bf(hi.w);
            } else {
                a[0] = 0; a[1] = 0; a[2] = 0; a[3] = 0;
                a[4] = 0; a[5] = 0; a[6] = 0; a[7] = 0;
            }
            afrag[kc] = a;
        }
    }

    const int onode_base = nodebase + ksel * 4;

#pragma unroll 1
    for (int i = 0; i < 4; i++) {
        f32x4 acc[4];
#pragma unroll
        for (int gb = 0; gb < 4; gb++) {
            float b = B2[gb * 64 + i * 16 + col];
            f32x4 c; c[0] = b; c[1] = b; c[2] = b; c[3] = b;
#pragma unroll
            for (int kc = 0; kc < 4; kc++) {
                bf16x8 bf = *(const bf16x8*)(W2bf
                    + (size_t)(gb * 64 + i * 16 + col) * KDIM + kc * 32 + ksel * 8);
                c = __builtin_amdgcn_mfma_f32_16x16x32_bf16(afrag[kc], bf, c, 0, 0, 0);
            }
            acc[gb] = c;
        }
#pragma unroll
        for (int r = 0; r < 4; r++) {
            int node = onode_base + r;
            if (node < n) {
                float rr = 1.f / (1.f + expf(-acc[0][r]));
                float z  = 1.f / (1.f + expf(-acc[1][r]));
                float nn = tanhf(acc[2][r] + rr * acc[3][r]);
                float hold = X1[(size_t)node * KDIM + hoff + i * 16 + col];
                X1[(size_t)node * KDIM + aoff + i * 16 + col] = (1.f - z) * nn + z * hold;
            }
        }
    }
}

// ---------------- output projection as tiled GEMM (proven) ----------------

__global__ __launch_bounds__(256) void out_gemm_kernel(
    const float* __restrict__ X1, const float* __restrict__ Wop,
    const float* __restrict__ b_out, float* __restrict__ out, int n, int hoff) {
    __shared__ float xs[NT * 68];          // 17.4 KB
    __shared__ float wsh[64 * WS_STRIDE];  // 5 KB

    const int t  = threadIdx.x;
    const int tx = t & 15;
    const int ty = t >> 4;
    const int node0 = blockIdx.x * NT;

#pragma unroll
    for (int i = 0; i < 4; i++) {
        int f4 = i * 256 + t;
        int r  = f4 >> 4;
        int c4 = f4 & 15;
        float4 v = make_float4(0.f, 0.f, 0.f, 0.f);
        int node = node0 + r;
        if (node < n) v = *(const float4*)(X1 + (size_t)node * KDIM + hoff + c4 * 4);
        *(float4*)(xs + r * 68 + c4 * 4) = v;
    }

    float acc[4][4];
#pragma unroll
    for (int i = 0; i < 4; i++) {
        float b = b_out[i * 16 + tx];
#pragma unroll
        for (int nd = 0; nd < 4; nd++) acc[nd][i] = b;
    }

    const float* wbase = wsh + tx * WS_STRIDE;
#pragma unroll 1
    for (int kc = 0; kc < 4; kc++) {
        __syncthreads();
        {
            const float4* src = (const float4*)(Wop + (size_t)kc * (64 * 16));
            int f4  = t;
            int row = f4 >> 2;
            int k4  = f4 & 3;
            *(float4*)(wsh + row * WS_STRIDE + k4 * 4) = src[f4];
        }
        __syncthreads();
        const float* xbase = xs + (ty * 4) * 68 + kc * 16;
#pragma unroll
        for (int k4 = 0; k4 < 4; k4++) {
            float4 xv[4];
#pragma unroll
            for (int nd = 0; nd < 4; nd++)
                xv[nd] = *(const float4*)(xbase + nd * 68 + k4 * 4);
#pragma unroll
            for (int i = 0; i < 4; i++) {
                float4 w = *(const float4*)(wbase + (i * 16) * WS_STRIDE + k4 * 4);
#pragma unroll
                for (int nd = 0; nd < 4; nd++) {
                    acc[nd][i] += w.x * xv[nd].x + w.y * xv[nd].y
                                + w.z * xv[nd].z + w.w * xv[nd].w;
                }
            }
        }
    }

#pragma unroll
    for (int nd = 0; nd < 4; nd++) {
        int node = node0 + ty * 4 + nd;
        if (node < n) {
#pragma unroll
            for (int i = 0; i < 4; i++)
                out[(size_t)node * HID + i * 16 + tx] = acc[nd][i];
        }
    }
}

// ---------------- launch ----------------

extern "C" void kernel_launch(void* const* d_in, const int* in_sizes, int n_in,
                              void* d_out, int out_size, void* d_ws, size_t ws_size,
                              hipStream_t stream) {
    const float* x     = (const float*)d_in[0];
    const int*   ei    = (const int*)d_in[1];
    const float* W_in  = (const float*)d_in[2];
    const float* b_in  = (const float*)d_in[3];
    const float* W_t1  = (const float*)d_in[4];
    const float* b_t1  = (const float*)d_in[5];
    const float* W_t2  = (const float*)d_in[6];
    const float* b_t2  = (const float*)d_in[7];
    const float* W_ih  = (const float*)d_in[8];
    const float* b_ih  = (const float*)d_in[9];
    const float* W_hh  = (const float*)d_in[10];
    const float* b_hh  = (const float*)d_in[11];
    const float* W_out = (const float*)d_in[12];
    const float* b_out = (const float*)d_in[13];
    float* out = (float*)d_out;

    const int n = in_sizes[0] / IN_DIM;  // 100000
    const int e = in_sizes[1] / 2;       // 1000000
    const int* row = ei;
    const int* col = ei + e;

    char* ws = (char*)d_ws;
    float* X1  = (float*)ws;  ws += (size_t)n * KDIM * sizeof(float);   // 51.2 MB
    unsigned short* W2bf = (unsigned short*)ws;  ws += (size_t)JOUT * KDIM * sizeof(unsigned short);
    unsigned short* W1bf = (unsigned short*)ws;  ws += (size_t)128 * IN_DIM * sizeof(unsigned short);
    float* B2  = (float*)ws;  ws += JOUT * sizeof(float);
    float* B1  = (float*)ws;  ws += 128 * sizeof(float);
    float* Wop = (float*)ws;  ws += (size_t)64 * HID * sizeof(float);
    float* tau = (float*)ws;  ws += (size_t)n * sizeof(float);
    int* deg       = (int*)ws;  ws += (size_t)n * sizeof(int);
    int* row_start = (int*)ws;  ws += (size_t)n * sizeof(int);
    int* cursor    = (int*)ws;  ws += (size_t)n * sizeof(int);
    int* blk       = (int*)ws;  ws += SCAN_B * sizeof(int);
    int* cols      = (int*)ws;  ws += (size_t)e * sizeof(int);

    const int nb = (n + SCAN_B - 1) / SCAN_B;
    const int ngemm = (n + NT - 1) / NT;

    zero_int_kernel<<<(n + 255) / 256, 256, 0, stream>>>(deg, n);
    count_deg_kernel<<<(e + 255) / 256, 256, 0, stream>>>(row, deg, e, n);
    block_sum_kernel<<<nb, SCAN_B, 0, stream>>>(deg, blk, n);
    scan_blk_kernel<<<1, SCAN_B, 0, stream>>>(blk, nb);
    scan_final_kernel<<<nb, SCAN_B, 0, stream>>>(deg, blk, row_start, cursor, n);
    fill_csr_kernel<<<(e + 255) / 256, 256, 0, stream>>>(row, col, cursor, cols, e, n);

    prep_all_kernel<<<1, 256, 0, stream>>>(W_ih, W_hh, b_ih, b_hh,
                                           W_in, b_in, W_t1, b_t1, W_out,
                                           W2bf, B2, W1bf, B1, Wop);
    init_mfma_kernel<<<ngemm, 256, 0, stream>>>(x, W1bf, B1, W_t2, b_t2, X1, tau, n);

    int hoff = 64, aoff = 0;  // h starts in cols [64,128)
    for (int it = 0; it < 5; ++it) {
        aggregate_kernel<<<((n * 16) + 255) / 256, 256, 0, stream>>>(
            X1, tau, row_start, deg, cols, n, hoff, aoff);
        gru_mfma_kernel<<<ngemm, 256, 0, stream>>>(X1, W2bf, B2, n, hoff, aoff);
        int tmp = hoff; hoff = aoff; aoff = tmp;  // h' now lives where agg was
    }
    out_gemm_kernel<<<ngemm, 256, 0, stream>>>(X1, Wop, b_out, out, n, hoff);
}

// Round 14
// 794.090 us; speedup vs baseline: 10.7738x; 1.1078x over previous
//
#include <hip/hip_runtime.h>

#define HID 64
#define IN_DIM 128
#define TAU_DIM 8
#define SCAN_B 1024

#define KDIM 128        // X row = [agg(64) | h(64)], bf16
#define NT 64           // nodes per GEMM block
#define JOUT 256        // padded gate outputs: [r(64) z(64) | i_n(64) | h_n(64)]
#define WS_STRIDE 20    // 16 + 4 pad (f32 words)

typedef short bf16x4 __attribute__((ext_vector_type(4)));   // 4 bf16 = 8B
typedef short bf16x8 __attribute__((ext_vector_type(8)));   // 8 bf16 = 16B
typedef float f32x4 __attribute__((ext_vector_type(4)));

__device__ __forceinline__ unsigned short f2bf(float f) {
    union { float f; unsigned u; } v; v.f = f;
    unsigned r = v.u + 0x7FFF + ((v.u >> 16) & 1);  // RNE
    return (unsigned short)(r >> 16);
}
__device__ __forceinline__ float bf2f(unsigned short s) {
    union { unsigned u; float f; } v; v.u = ((unsigned)s) << 16;
    return v.f;
}

// ---------------- CSR build (bounds-guarded) ----------------

__global__ void zero_int_kernel(int* __restrict__ p, int n) {
    int i = blockIdx.x * blockDim.x + threadIdx.x;
    if (i < n) p[i] = 0;
}

__global__ void count_deg_kernel(const int* __restrict__ row, int* __restrict__ deg,
                                 int e, int n) {
    int i = blockIdx.x * blockDim.x + threadIdx.x;
    if (i < e) {
        int r = row[i];
        if ((unsigned)r < (unsigned)n) atomicAdd(&deg[r], 1);
    }
}

__global__ void block_sum_kernel(const int* __restrict__ deg, int* __restrict__ blk, int n) {
    __shared__ int s[SCAN_B];
    int i = blockIdx.x * SCAN_B + threadIdx.x;
    s[threadIdx.x] = (i < n) ? deg[i] : 0;
    __syncthreads();
    for (int off = SCAN_B / 2; off > 0; off >>= 1) {
        if (threadIdx.x < off) s[threadIdx.x] += s[threadIdx.x + off];
        __syncthreads();
    }
    if (threadIdx.x == 0) blk[blockIdx.x] = s[0];
}

__global__ void scan_blk_kernel(int* __restrict__ blk, int nb) {
    __shared__ int s[SCAN_B];
    int v = (threadIdx.x < nb) ? blk[threadIdx.x] : 0;
    s[threadIdx.x] = v;
    __syncthreads();
    for (int off = 1; off < SCAN_B; off <<= 1) {
        int t = (threadIdx.x >= off) ? s[threadIdx.x - off] : 0;
        __syncthreads();
        s[threadIdx.x] += t;
        __syncthreads();
    }
    if (threadIdx.x < nb) blk[threadIdx.x] = s[threadIdx.x] - v;  // exclusive
}

__global__ void scan_final_kernel(const int* __restrict__ deg, const int* __restrict__ blk,
                                  int* __restrict__ row_start, int* __restrict__ cursor, int n) {
    __shared__ int s[SCAN_B];
    int i = blockIdx.x * SCAN_B + threadIdx.x;
    int v = (i < n) ? deg[i] : 0;
    s[threadIdx.x] = v;
    __syncthreads();
    for (int off = 1; off < SCAN_B; off <<= 1) {
        int t = (threadIdx.x >= off) ? s[threadIdx.x - off] : 0;
        __syncthreads();
        s[threadIdx.x] += t;
        __syncthreads();
    }
    if (i < n) {
        int excl = s[threadIdx.x] - v + blk[blockIdx.x];
        row_start[i] = excl;
        cursor[i]    = excl;
    }
}

__global__ void fill_csr_kernel(const int* __restrict__ row, const int* __restrict__ col,
                                int* __restrict__ cursor, int* __restrict__ cols,
                                int e, int n) {
    int i = blockIdx.x * blockDim.x + threadIdx.x;
    if (i < e) {
        int r = row[i];
        if ((unsigned)r < (unsigned)n) {
            int c = col[i];
            if ((unsigned)c >= (unsigned)n) c = 0;
            int p = atomicAdd(&cursor[r], 1);
            cols[p] = c;
        }
    }
}

// ---------------- weight repacks (round-13 proven) ----------------

__global__ void prep_all_kernel(
    const float* __restrict__ W_ih, const float* __restrict__ W_hh,
    const float* __restrict__ b_ih, const float* __restrict__ b_hh,
    const float* __restrict__ W_in, const float* __restrict__ b_in,
    const float* __restrict__ W_t1, const float* __restrict__ b_t1,
    const float* __restrict__ W_out,
    unsigned short* __restrict__ W2bf, float* __restrict__ B2,
    unsigned short* __restrict__ W1bf, float* __restrict__ B1,
    float* __restrict__ Wop) {
    int j = threadIdx.x;  // 256 threads, 1 block
    {
        float b;
        if (j < 128)      b = b_ih[j] + b_hh[j];
        else if (j < 192) b = b_ih[j];
        else              b = b_hh[j - 64];
        B2[j] = b;
        for (int k = 0; k < KDIM; k++) {
            float v;
            if (j < 128)      v = (k < 64) ? W_ih[j * 64 + k] : W_hh[j * 64 + (k - 64)];
            else if (j < 192) v = (k < 64) ? W_ih[j * 64 + k] : 0.f;
            else              v = (k >= 64) ? W_hh[(j - 64) * 64 + (k - 64)] : 0.f;
            W2bf[(size_t)j * KDIM + k] = f2bf(v);
        }
    }
    if (j < 128) {
        B1[j] = (j < 64) ? b_in[j] : b_t1[j - 64];
        const float* src = (j < 64) ? (W_in + (size_t)j * IN_DIM)
                                    : (W_t1 + (size_t)(j - 64) * IN_DIM);
        for (int k = 0; k < IN_DIM; k++)
            W1bf[(size_t)j * IN_DIM + k] = f2bf(src[k]);
    }
    if (j < 64) {
        for (int k = 0; k < HID; k++)
            Wop[(size_t)(k >> 4) * (64 * 16) + j * 16 + (k & 15)] = W_out[(size_t)j * HID + k];
    }
}

// ---------------- init via MFMA: h0(bf16) + tau (round-13 proven structure) ----------------

__global__ __launch_bounds__(256) void init_mfma_kernel(
    const float* __restrict__ x, const unsigned short* __restrict__ W1bf,
    const float* __restrict__ B1,
    const float* __restrict__ W_t2, const float* __restrict__ b_t2,
    unsigned short* __restrict__ X1, float* __restrict__ tau, int n) {
    __shared__ float t1s[NT * 65];  // 16.6 KB

    const int t    = threadIdx.x;
    const int lane = t & 63;
    const int wave = t >> 6;
    const int col  = lane & 15;
    const int ksel = lane >> 4;  // 0..3
    const int nodebase = blockIdx.x * NT + wave * 16;

    bf16x8 afrag[4];
    {
        const int anode = nodebase + col;
#pragma unroll
        for (int kc = 0; kc < 4; kc++) {
            bf16x8 a;
            if (anode < n) {
                const float* p = x + (size_t)anode * IN_DIM + kc * 32 + ksel * 8;
                float4 lo = *(const float4*)p;
                float4 hi = *(const float4*)(p + 4);
                a[0] = (short)f2bf(lo.x); a[1] = (short)f2bf(lo.y);
                a[2] = (short)f2bf(lo.z); a[3] = (short)f2bf(lo.w);
                a[4] = (short)f2bf(hi.x); a[5] = (short)f2bf(hi.y);
                a[6] = (short)f2bf(hi.z); a[7] = (short)f2bf(hi.w);
            } else {
                a[0] = 0; a[1] = 0; a[2] = 0; a[3] = 0;
                a[4] = 0; a[5] = 0; a[6] = 0; a[7] = 0;
            }
            afrag[kc] = a;
        }
    }

#pragma unroll 1
    for (int i = 0; i < 8; i++) {   // j-group: cols i*16 .. i*16+16
        float b = B1[i * 16 + col];
        f32x4 c; c[0] = b; c[1] = b; c[2] = b; c[3] = b;
#pragma unroll
        for (int kc = 0; kc < 4; kc++) {
            bf16x8 bf = *(const bf16x8*)(W1bf
                + (size_t)(i * 16 + col) * IN_DIM + kc * 32 + ksel * 8);
            c = __builtin_amdgcn_mfma_f32_16x16x32_bf16(afrag[kc], bf, c, 0, 0, 0);
        }
#pragma unroll
        for (int r = 0; r < 4; r++) {
            int node = nodebase + ksel * 4 + r;
            float v = fmaxf(c[r], 0.f);
            if (i < 4) {
                if (node < n) X1[(size_t)node * KDIM + 64 + i * 16 + col] = f2bf(v);
            } else {
                t1s[(wave * 16 + ksel * 4 + r) * 65 + (i - 4) * 16 + col] = v;
            }
        }
    }
    __syncthreads();

    if (t < NT) {
        int node = blockIdx.x * NT + t;
        if (node < n) {
            float tsum = 0.f;
#pragma unroll 1
            for (int m = 0; m < TAU_DIM; m++) {
                float a = b_t2[m];
                const float* wr = W_t2 + (size_t)m * HID;
#pragma unroll
                for (int k = 0; k < HID; k++) a += wr[k] * t1s[t * 65 + k];
                tsum += 1.f / (1.f + expf(-a));
            }
            tau[node] = tsum * (1.f / TAU_DIM);
        }
    }
}

// ---------------- aggregate (bf16 X): X1[v][aoff..] = tau[v] * sum |h[v]-h[col]| ----------------
// 16 lanes/node, bf16x4 (8B) per lane: gather traffic halved vs fp32.
// Accumulation in fp32; result stored bf16 (was already bf16-rounded at the
// GEMM A-frag load in round 11-13, so no new error on this path).

__global__ __launch_bounds__(256) void aggregate_kernel(
    unsigned short* __restrict__ X1, const float* __restrict__ tau,
    const int* __restrict__ row_start, const int* __restrict__ deg,
    const int* __restrict__ cols, int n, int hoff, int aoff) {
    int t = blockIdx.x * blockDim.x + threadIdx.x;
    int v = t >> 4;
    if (v >= n) return;
    int c4 = (t & 15) * 4;

    bf16x4 hvb = *(const bf16x4*)(X1 + (size_t)v * KDIM + hoff + c4);
    float h0 = bf2f((unsigned short)hvb[0]), h1 = bf2f((unsigned short)hvb[1]);
    float h2 = bf2f((unsigned short)hvb[2]), h3 = bf2f((unsigned short)hvb[3]);
    float s00 = 0.f, s01 = 0.f, s02 = 0.f, s03 = 0.f;
    float s10 = 0.f, s11 = 0.f, s12 = 0.f, s13 = 0.f;
    int st = row_start[v];
    int d  = deg[v];
    int i = 0;
    for (; i + 1 < d; i += 2) {
        int c0 = cols[st + i];
        int c1 = cols[st + i + 1];
        bf16x4 a = *(const bf16x4*)(X1 + (size_t)c0 * KDIM + hoff + c4);
        bf16x4 b = *(const bf16x4*)(X1 + (size_t)c1 * KDIM + hoff + c4);
        s00 += fabsf(h0 - bf2f((unsigned short)a[0]));
        s01 += fabsf(h1 - bf2f((unsigned short)a[1]));
        s02 += fabsf(h2 - bf2f((unsigned short)a[2]));
        s03 += fabsf(h3 - bf2f((unsigned short)a[3]));
        s10 += fabsf(h0 - bf2f((unsigned short)b[0]));
        s11 += fabsf(h1 - bf2f((unsigned short)b[1]));
        s12 += fabsf(h2 - bf2f((unsigned short)b[2]));
        s13 += fabsf(h3 - bf2f((unsigned short)b[3]));
    }
    if (i < d) {
        int c = cols[st + i];
        bf16x4 a = *(const bf16x4*)(X1 + (size_t)c * KDIM + hoff + c4);
        s00 += fabsf(h0 - bf2f((unsigned short)a[0]));
        s01 += fabsf(h1 - bf2f((unsigned short)a[1]));
        s02 += fabsf(h2 - bf2f((unsigned short)a[2]));
        s03 += fabsf(h3 - bf2f((unsigned short)a[3]));
    }
    float tv = tau[v];
    bf16x4 o;
    o[0] = (short)f2bf((s00 + s10) * tv);
    o[1] = (short)f2bf((s01 + s11) * tv);
    o[2] = (short)f2bf((s02 + s12) * tv);
    o[3] = (short)f2bf((s03 + s13) * tv);
    *(bf16x4*)(X1 + (size_t)v * KDIM + aoff + c4) = o;
}

// ---------------- GRU via MFMA (bf16 X: direct A-frag loads, no cvt) ----------------
// Revert plan: if validation fails, restore round-13 fp32-X1 source (880 us).

__global__ __launch_bounds__(256) void gru_mfma_kernel(
    unsigned short* __restrict__ X1, const unsigned short* __restrict__ W2bf,
    const float* __restrict__ B2, int n, int hoff, int aoff) {
    const int t    = threadIdx.x;
    const int lane = t & 63;
    const int wave = t >> 6;
    const int col  = lane & 15;
    const int ksel = lane >> 4;  // 0..3
    const int nodebase = blockIdx.x * NT + wave * 16;

    bf16x8 afrag[4];
    {
        const int anode = nodebase + col;
#pragma unroll
        for (int kc = 0; kc < 4; kc++) {
            int c0 = ((kc < 2) ? (aoff + kc * 32) : (hoff + (kc - 2) * 32)) + ksel * 8;
            bf16x8 a;
            if (anode < n) {
                a = *(const bf16x8*)(X1 + (size_t)anode * KDIM + c0);
            } else {
                a[0] = 0; a[1] = 0; a[2] = 0; a[3] = 0;
                a[4] = 0; a[5] = 0; a[6] = 0; a[7] = 0;
            }
            afrag[kc] = a;
        }
    }

    const int onode_base = nodebase + ksel * 4;

#pragma unroll 1
    for (int i = 0; i < 4; i++) {
        f32x4 acc[4];
#pragma unroll
        for (int gb = 0; gb < 4; gb++) {
            float b = B2[gb * 64 + i * 16 + col];
            f32x4 c; c[0] = b; c[1] = b; c[2] = b; c[3] = b;
#pragma unroll
            for (int kc = 0; kc < 4; kc++) {
                bf16x8 bf = *(const bf16x8*)(W2bf
                    + (size_t)(gb * 64 + i * 16 + col) * KDIM + kc * 32 + ksel * 8);
                c = __builtin_amdgcn_mfma_f32_16x16x32_bf16(afrag[kc], bf, c, 0, 0, 0);
            }
            acc[gb] = c;
        }
#pragma unroll
        for (int r = 0; r < 4; r++) {
            int node = onode_base + r;
            if (node < n) {
                float rr = 1.f / (1.f + expf(-acc[0][r]));
                float z  = 1.f / (1.f + expf(-acc[1][r]));
                float nn = tanhf(acc[2][r] + rr * acc[3][r]);
                float hold = bf2f(X1[(size_t)node * KDIM + hoff + i * 16 + col]);
                X1[(size_t)node * KDIM + aoff + i * 16 + col] =
                    f2bf((1.f - z) * nn + z * hold);
            }
        }
    }
}

// ---------------- output projection as tiled GEMM (bf16 h staged to fp32 LDS) ----------------

__global__ __launch_bounds__(256) void out_gemm_kernel(
    const unsigned short* __restrict__ X1, const float* __restrict__ Wop,
    const float* __restrict__ b_out, float* __restrict__ out, int n, int hoff) {
    __shared__ float xs[NT * 68];          // 17.4 KB
    __shared__ float wsh[64 * WS_STRIDE];  // 5 KB

    const int t  = threadIdx.x;
    const int tx = t & 15;
    const int ty = t >> 4;
    const int node0 = blockIdx.x * NT;

#pragma unroll
    for (int i = 0; i < 2; i++) {
        int idx = i * 256 + t;   // 0..511
        int r   = idx >> 3;      // row 0..63
        int c8  = (idx & 7) * 8; // col group
        int node = node0 + r;
        float vals[8];
        if (node < n) {
            bf16x8 v8 = *(const bf16x8*)(X1 + (size_t)node * KDIM + hoff + c8);
#pragma unroll
            for (int j = 0; j < 8; j++) vals[j] = bf2f((unsigned short)v8[j]);
        } else {
#pragma unroll
            for (int j = 0; j < 8; j++) vals[j] = 0.f;
        }
#pragma unroll
        for (int j = 0; j < 8; j++) xs[r * 68 + c8 + j] = vals[j];
    }

    float acc[4][4];
#pragma unroll
    for (int i = 0; i < 4; i++) {
        float b = b_out[i * 16 + tx];
#pragma unroll
        for (int nd = 0; nd < 4; nd++) acc[nd][i] = b;
    }

    const float* wbase = wsh + tx * WS_STRIDE;
#pragma unroll 1
    for (int kc = 0; kc < 4; kc++) {
        __syncthreads();
        {
            const float4* src = (const float4*)(Wop + (size_t)kc * (64 * 16));
            int f4  = t;
            int row = f4 >> 2;
            int k4  = f4 & 3;
            *(float4*)(wsh + row * WS_STRIDE + k4 * 4) = src[f4];
        }
        __syncthreads();
        const float* xbase = xs + (ty * 4) * 68 + kc * 16;
#pragma unroll
        for (int k4 = 0; k4 < 4; k4++) {
            float4 xv[4];
#pragma unroll
            for (int nd = 0; nd < 4; nd++)
                xv[nd] = *(const float4*)(xbase + nd * 68 + k4 * 4);
#pragma unroll
            for (int i = 0; i < 4; i++) {
                float4 w = *(const float4*)(wbase + (i * 16) * WS_STRIDE + k4 * 4);
#pragma unroll
                for (int nd = 0; nd < 4; nd++) {
                    acc[nd][i] += w.x * xv[nd].x + w.y * xv[nd].y
                                + w.z * xv[nd].z + w.w * xv[nd].w;
                }
            }
        }
    }

#pragma unroll
    for (int nd = 0; nd < 4; nd++) {
        int node = node0 + ty * 4 + nd;
        if (node < n) {
#pragma unroll
            for (int i = 0; i < 4; i++)
                out[(size_t)node * HID + i * 16 + tx] = acc[nd][i];
        }
    }
}

// ---------------- launch ----------------

extern "C" void kernel_launch(void* const* d_in, const int* in_sizes, int n_in,
                              void* d_out, int out_size, void* d_ws, size_t ws_size,
                              hipStream_t stream) {
    const float* x     = (const float*)d_in[0];
    const int*   ei    = (const int*)d_in[1];
    const float* W_in  = (const float*)d_in[2];
    const float* b_in  = (const float*)d_in[3];
    const float* W_t1  = (const float*)d_in[4];
    const float* b_t1  = (const float*)d_in[5];
    const float* W_t2  = (const float*)d_in[6];
    const float* b_t2  = (const float*)d_in[7];
    const float* W_ih  = (const float*)d_in[8];
    const float* b_ih  = (const float*)d_in[9];
    const float* W_hh  = (const float*)d_in[10];
    const float* b_hh  = (const float*)d_in[11];
    const float* W_out = (const float*)d_in[12];
    const float* b_out = (const float*)d_in[13];
    float* out = (float*)d_out;

    const int n = in_sizes[0] / IN_DIM;  // 100000
    const int e = in_sizes[1] / 2;       // 1000000
    const int* row = ei;
    const int* col = ei + e;

    char* ws = (char*)d_ws;
    unsigned short* X1 = (unsigned short*)ws;  ws += (size_t)n * KDIM * sizeof(unsigned short);  // 25.6 MB
    unsigned short* W2bf = (unsigned short*)ws;  ws += (size_t)JOUT * KDIM * sizeof(unsigned short);
    unsigned short* W1bf = (unsigned short*)ws;  ws += (size_t)128 * IN_DIM * sizeof(unsigned short);
    float* B2  = (float*)ws;  ws += JOUT * sizeof(float);
    float* B1  = (float*)ws;  ws += 128 * sizeof(float);
    float* Wop = (float*)ws;  ws += (size_t)64 * HID * sizeof(float);
    float* tau = (float*)ws;  ws += (size_t)n * sizeof(float);
    int* deg       = (int*)ws;  ws += (size_t)n * sizeof(int);
    int* row_start = (int*)ws;  ws += (size_t)n * sizeof(int);
    int* cursor    = (int*)ws;  ws += (size_t)n * sizeof(int);
    int* blk       = (int*)ws;  ws += SCAN_B * sizeof(int);
    int* cols      = (int*)ws;  ws += (size_t)e * sizeof(int);

    const int nb = (n + SCAN_B - 1) / SCAN_B;
    const int ngemm = (n + NT - 1) / NT;

    zero_int_kernel<<<(n + 255) / 256, 256, 0, stream>>>(deg, n);
    count_deg_kernel<<<(e + 255) / 256, 256, 0, stream>>>(row, deg, e, n);
    block_sum_kernel<<<nb, SCAN_B, 0, stream>>>(deg, blk, n);
    scan_blk_kernel<<<1, SCAN_B, 0, stream>>>(blk, nb);
    scan_final_kernel<<<nb, SCAN_B, 0, stream>>>(deg, blk, row_start, cursor, n);
    fill_csr_kernel<<<(e + 255) / 256, 256, 0, stream>>>(row, col, cursor, cols, e, n);

    prep_all_kernel<<<1, 256, 0, stream>>>(W_ih, W_hh, b_ih, b_hh,
                                           W_in, b_in, W_t1, b_t1, W_out,
                                           W2bf, B2, W1bf, B1, Wop);
    init_mfma_kernel<<<ngemm, 256, 0, stream>>>(x, W1bf, B1, W_t2, b_t2, X1, tau, n);

    int hoff = 64, aoff = 0;  // h starts in cols [64,128)
    for (int it = 0; it < 5; ++it) {
        aggregate_kernel<<<((n * 16) + 255) / 256, 256, 0, stream>>>(
            X1, tau, row_start, deg, cols, n, hoff, aoff);
        gru_mfma_kernel<<<ngemm, 256, 0, stream>>>(X1, W2bf, B2, n, hoff, aoff);
        int tmp = hoff; hoff = aoff; aoff = tmp;  // h' now lives where agg was
    }
    out_gemm_kernel<<<ngemm, 256, 0, stream>>>(X1, Wop, b_out, out, n, hoff);
}